// Round 19
// baseline (444.493 us; speedup 1.0000x reference)
//
#include <hip/hip_runtime.h>
#include <math.h>

// ---------------- problem constants ----------------
constexpr int cH = 8;
constexpr int cDP = 128;
constexpr int cM = 64;
constexpr int cB = 16;
constexpr int cNCTX = 3200;
constexpr int cNQ = 3072;
constexpr int cSHIFT = 128;
constexpr int ROWS_Q = 2 * cB * cNQ;    // 98304
constexpr int ROWS_KV = cB * cNCTX;     // 51200
constexpr float cRATIO = 0.125f;
constexpr float cEPST = 0.125e-4f;
constexpr float cLNEPS = 1e-5f;

typedef float f32x4 __attribute__((ext_vector_type(4)));
typedef short short8 __attribute__((ext_vector_type(8)));
typedef _Float16 half2 __attribute__((ext_vector_type(2)));

#define MFMA16x16(a, b, c) __builtin_amdgcn_mfma_f32_16x16x32_bf16((a), (b), (c), 0, 0, 0)

__device__ __forceinline__ float wmax64(float v) {
#pragma unroll
  for (int o = 32; o; o >>= 1) v = fmaxf(v, __shfl_xor(v, o));
  return v;
}
__device__ __forceinline__ float wsum64(float v) {
#pragma unroll
  for (int o = 32; o; o >>= 1) v += __shfl_xor(v, o);
  return v;
}
__device__ __forceinline__ float gelu_f(float x) {
  return 0.5f * x * (1.0f + tanhf(0.79788456080286536f * (x + 0.044715f * x * x * x)));
}
// fp32 -> bf16 (RTNE), low 16 bits
__device__ __forceinline__ unsigned int bf16r(float f) {
  unsigned int x = __float_as_uint(f);
  return (x + 0x7fffu + ((x >> 16) & 1u)) >> 16;
}
// fp32 -> fp16 (RTNE), low 16 bits
__device__ __forceinline__ unsigned int f16r(float f) {
  _Float16 hh = (_Float16)f;
  unsigned short u;
  __builtin_memcpy(&u, &hh, 2);
  return (unsigned int)u;
}
// 8 packed bf16 (uint4) -> 8 floats
__device__ __forceinline__ void cvt8(uint4 u, float f[8]) {
  f[0] = __uint_as_float(u.x << 16);
  f[1] = __uint_as_float(u.x & 0xffff0000u);
  f[2] = __uint_as_float(u.y << 16);
  f[3] = __uint_as_float(u.y & 0xffff0000u);
  f[4] = __uint_as_float(u.z << 16);
  f[5] = __uint_as_float(u.z & 0xffff0000u);
  f[6] = __uint_as_float(u.w << 16);
  f[7] = __uint_as_float(u.w & 0xffff0000u);
}
// swizzled ushort index for element (row, k) in a [*][128] 16-bit tile
__device__ __forceinline__ int swz(int row, int k) {
  return row * 128 + ((((k >> 3) ^ (row & 15)) << 3) | (k & 7));
}

// ============ K0: weight prep -> 16-bit, [n][k] layout, pre-swizzled (R18 exact) ============
__global__ __launch_bounds__(256) void k0_prep(
    const float* __restrict__ fcw, const float* __restrict__ prw,
    const float* __restrict__ wq, const float* __restrict__ wo,
    unsigned short* __restrict__ fcT, unsigned short* __restrict__ prT,
    unsigned short* __restrict__ wqT, unsigned short* __restrict__ woT) {
  const int mat = blockIdx.x;
  const float* src = mat == 0 ? fcw : mat == 1 ? prw : mat == 2 ? wq : wo;
  unsigned short* dst = mat == 0 ? fcT : mat == 1 ? prT : mat == 2 ? wqT : woT;
  const bool tr = (mat < 2);   // fc_w/pr_w are [k][n]; wq/wo are [n][k]
  for (int i = threadIdx.x; i < 16384; i += 256) {
    int n = i >> 7, k = i & 127;
    float f = tr ? src[k * 128 + n] : src[i];
    dst[swz(n, k)] = (unsigned short)(mat == 2 ? f16r(f) : bf16r(f));
  }
}

// ============ K1: MLP (LN4 -> fc -> gelu -> pr -> +y), MFMA, 256 threads (R18 exact) ============
__global__ __launch_bounds__(256, 2) void k1_mlp(
    const float* __restrict__ y,
    const float* __restrict__ ln4w, const float* __restrict__ ln4b,
    const unsigned short* __restrict__ fcT, const float* __restrict__ fcb,
    const unsigned short* __restrict__ prT, const float* __restrict__ prb,
    float* __restrict__ y1) {
  __shared__ unsigned short wfc[16384];
  __shared__ unsigned short wpr[16384];
  __shared__ unsigned short xb[4096];
  __shared__ unsigned short hb[4096];
  const int tid = threadIdx.x;
  {
    const uint4* s1 = (const uint4*)fcT; uint4* d1 = (uint4*)wfc;
    const uint4* s2 = (const uint4*)prT; uint4* d2 = (uint4*)wpr;
    for (int i = tid; i < 2048; i += 256) { d1[i] = s1[i]; d2[i] = s2[i]; }
  }
  const int lane = tid & 63, wv = tid >> 6;
  const int lrow = tid >> 3, lsub = tid & 7;
  const int colbase = wv * 32;
  float fb[2], pb[2];
#pragma unroll
  for (int ct = 0; ct < 2; ++ct) {
    int col = colbase + ct * 16 + (lane & 15);
    fb[ct] = fcb[col];
    pb[ct] = prb[col];
  }
  float lw[16], lb[16];
  *(float4*)&lw[0] = *(const float4*)(ln4w + lsub * 16 + 0);
  *(float4*)&lw[4] = *(const float4*)(ln4w + lsub * 16 + 4);
  *(float4*)&lw[8] = *(const float4*)(ln4w + lsub * 16 + 8);
  *(float4*)&lw[12] = *(const float4*)(ln4w + lsub * 16 + 12);
  *(float4*)&lb[0] = *(const float4*)(ln4b + lsub * 16 + 0);
  *(float4*)&lb[4] = *(const float4*)(ln4b + lsub * 16 + 4);
  *(float4*)&lb[8] = *(const float4*)(ln4b + lsub * 16 + 8);
  *(float4*)&lb[12] = *(const float4*)(ln4b + lsub * 16 + 12);
  uint4* xb4 = (uint4*)xb;
  __syncthreads();

  for (int g = blockIdx.x; g < ROWS_Q / 32; g += gridDim.x) {
    const int r0 = g * 32;
    {  // LN4 -> xb (bf16 swizzled)
      const float* yr = y + (size_t)(r0 + lrow) * 128 + lsub * 16;
      float v[16];
      *(float4*)&v[0] = *(const float4*)(yr + 0);
      *(float4*)&v[4] = *(const float4*)(yr + 4);
      *(float4*)&v[8] = *(const float4*)(yr + 8);
      *(float4*)&v[12] = *(const float4*)(yr + 12);
      float s = 0.f, q = 0.f;
#pragma unroll
      for (int j = 0; j < 16; ++j) { s += v[j]; q += v[j] * v[j]; }
#pragma unroll
      for (int o = 1; o <= 4; o <<= 1) { s += __shfl_xor(s, o); q += __shfl_xor(q, o); }
      float mu = s * (1.0f / 128.0f);
      float rs = rsqrtf(q * (1.0f / 128.0f) - mu * mu + cLNEPS);
      unsigned int us[8];
#pragma unroll
      for (int j = 0; j < 8; ++j) {
        float f0 = (v[2 * j] - mu) * rs * lw[2 * j] + lb[2 * j];
        float f1 = (v[2 * j + 1] - mu) * rs * lw[2 * j + 1] + lb[2 * j + 1];
        us[j] = bf16r(f0) | (bf16r(f1) << 16);
      }
      int s0 = (lsub * 2) ^ (lrow & 15), s1 = (lsub * 2 + 1) ^ (lrow & 15);
      xb4[lrow * 16 + s0] = make_uint4(us[0], us[1], us[2], us[3]);
      xb4[lrow * 16 + s1] = make_uint4(us[4], us[5], us[6], us[7]);
    }
    __syncthreads();
    {  // GEMM1 (MFMA) + gelu -> hb
      f32x4 acc[2][2] = {{{0.f,0.f,0.f,0.f},{0.f,0.f,0.f,0.f}},
                         {{0.f,0.f,0.f,0.f},{0.f,0.f,0.f,0.f}}};
#pragma unroll
      for (int kc = 0; kc < 4; ++kc) {
        short8 af[2], bfv[2];
#pragma unroll
        for (int rt = 0; rt < 2; ++rt) {
          int row = rt * 16 + (lane & 15);
          int slot = ((lane >> 4) + kc * 4) ^ (row & 15);
          af[rt] = *(const short8*)&xb[row * 128 + slot * 8];
        }
#pragma unroll
        for (int ct = 0; ct < 2; ++ct) {
          int col = colbase + ct * 16 + (lane & 15);
          int slot = ((lane >> 4) + kc * 4) ^ (col & 15);
          bfv[ct] = *(const short8*)&wfc[col * 128 + slot * 8];
        }
#pragma unroll
        for (int rt = 0; rt < 2; ++rt)
#pragma unroll
          for (int ct = 0; ct < 2; ++ct)
            acc[rt][ct] = MFMA16x16(af[rt], bfv[ct], acc[rt][ct]);
      }
#pragma unroll
      for (int rt = 0; rt < 2; ++rt)
#pragma unroll
        for (int ct = 0; ct < 2; ++ct) {
          int col = colbase + ct * 16 + (lane & 15);
#pragma unroll
          for (int reg = 0; reg < 4; ++reg) {
            int row = rt * 16 + (lane >> 4) * 4 + reg;
            hb[swz(row, col)] = (unsigned short)bf16r(gelu_f(acc[rt][ct][reg] + fb[ct]));
          }
        }
    }
    __syncthreads();
    {  // GEMM2 (MFMA) + bias + residual -> y1
      f32x4 a2[2][2] = {{{0.f,0.f,0.f,0.f},{0.f,0.f,0.f,0.f}},
                        {{0.f,0.f,0.f,0.f},{0.f,0.f,0.f,0.f}}};
#pragma unroll
      for (int kc = 0; kc < 4; ++kc) {
        short8 af[2], bfv[2];
#pragma unroll
        for (int rt = 0; rt < 2; ++rt) {
          int row = rt * 16 + (lane & 15);
          int slot = ((lane >> 4) + kc * 4) ^ (row & 15);
          af[rt] = *(const short8*)&hb[row * 128 + slot * 8];
        }
#pragma unroll
        for (int ct = 0; ct < 2; ++ct) {
          int col = colbase + ct * 16 + (lane & 15);
          int slot = ((lane >> 4) + kc * 4) ^ (col & 15);
          bfv[ct] = *(const short8*)&wpr[col * 128 + slot * 8];
        }
#pragma unroll
        for (int rt = 0; rt < 2; ++rt)
#pragma unroll
          for (int ct = 0; ct < 2; ++ct)
            a2[rt][ct] = MFMA16x16(af[rt], bfv[ct], a2[rt][ct]);
      }
#pragma unroll
      for (int rt = 0; rt < 2; ++rt)
#pragma unroll
        for (int ct = 0; ct < 2; ++ct) {
          int col = colbase + ct * 16 + (lane & 15);
#pragma unroll
          for (int reg = 0; reg < 4; ++reg) {
            int row = rt * 16 + (lane >> 4) * 4 + reg;
            size_t o = (size_t)(r0 + row) * 128 + col;
            y1[o] = a2[rt][ct][reg] + pb[ct] + y[o];
          }
        }
    }
    __syncthreads();
  }
}

// ============ K2: LN2(x) -> k,v projections (R18 exact) ============
__global__ __launch_bounds__(512) void k2_kv(
    const float* __restrict__ x,
    const float* __restrict__ ln2w, const float* __restrict__ ln2b,
    const float* __restrict__ wkw, const float* __restrict__ wvw,
    float* __restrict__ kbuf, float* __restrict__ vbuf) {
  __shared__ float wkT[32 * cDP];
  __shared__ float wvT[32 * cDP];
  __shared__ float xbs[16][32];
  const int tid = threadIdx.x;
  for (int i = tid; i < 32 * cDP; i += 512) {
    int j = i >> 5, d = i & 31;
    wkT[d * cDP + j] = wkw[i];
    wvT[d * cDP + j] = wvw[i];
  }
  const int dl = tid & 31, rl = tid >> 5;
  const int col = tid & 127, rh = tid >> 7;
  const float l2w = ln2w[dl], l2b = ln2b[dl];
  __syncthreads();
  for (int g = blockIdx.x; g < ROWS_KV / 16; g += gridDim.x) {
    const int r0 = g * 16;
    __syncthreads();
    {
      float v = x[(size_t)(r0 + rl) * 32 + dl];
      float s = v, q = v * v;
#pragma unroll
      for (int o = 16; o; o >>= 1) { s += __shfl_xor(s, o); q += __shfl_xor(q, o); }
      float mu = s * (1.0f / 32.0f);
      float var = q * (1.0f / 32.0f) - mu * mu;
      xbs[rl][dl] = (v - mu) * rsqrtf(var + cLNEPS) * l2w + l2b;
    }
    __syncthreads();
    float ak0 = 0, ak1 = 0, ak2 = 0, ak3 = 0, av0 = 0, av1 = 0, av2 = 0, av3 = 0;
    for (int d = 0; d < 32; d += 4) {
      float4 v0 = *(const float4*)&xbs[rh * 4 + 0][d];
      float4 v1 = *(const float4*)&xbs[rh * 4 + 1][d];
      float4 v2 = *(const float4*)&xbs[rh * 4 + 2][d];
      float4 v3 = *(const float4*)&xbs[rh * 4 + 3][d];
      float k0 = wkT[(d + 0) * cDP + col], k1 = wkT[(d + 1) * cDP + col];
      float k2 = wkT[(d + 2) * cDP + col], k3 = wkT[(d + 3) * cDP + col];
      float u0 = wvT[(d + 0) * cDP + col], u1 = wvT[(d + 1) * cDP + col];
      float u2 = wvT[(d + 2) * cDP + col], u3 = wvT[(d + 3) * cDP + col];
      ak0 += v0.x * k0 + v0.y * k1 + v0.z * k2 + v0.w * k3;
      ak1 += v1.x * k0 + v1.y * k1 + v1.z * k2 + v1.w * k3;
      ak2 += v2.x * k0 + v2.y * k1 + v2.z * k2 + v2.w * k3;
      ak3 += v3.x * k0 + v3.y * k1 + v3.z * k2 + v3.w * k3;
      av0 += v0.x * u0 + v0.y * u1 + v0.z * u2 + v0.w * u3;
      av1 += v1.x * u0 + v1.y * u1 + v1.z * u2 + v1.w * u3;
      av2 += v2.x * u0 + v2.y * u1 + v2.z * u2 + v2.w * u3;
      av3 += v3.x * u0 + v3.y * u1 + v3.z * u2 + v3.w * u3;
    }
    kbuf[(size_t)(r0 + rh * 4 + 0) * cDP + col] = ak0;
    kbuf[(size_t)(r0 + rh * 4 + 1) * cDP + col] = ak1;
    kbuf[(size_t)(r0 + rh * 4 + 2) * cDP + col] = ak2;
    kbuf[(size_t)(r0 + rh * 4 + 3) * cDP + col] = ak3;
    vbuf[(size_t)(r0 + rh * 4 + 0) * cDP + col] = av0;
    vbuf[(size_t)(r0 + rh * 4 + 1) * cDP + col] = av1;
    vbuf[(size_t)(r0 + rh * 4 + 2) * cDP + col] = av2;
    vbuf[(size_t)(r0 + rh * 4 + 3) * cDP + col] = av3;
  }
}

// ============ K4: k features + temporal-split windowed writes (R18 exact) ============
__global__ __launch_bounds__(512) void k4_kun(
    const float* __restrict__ kbuf, const float* __restrict__ proj,
    float* __restrict__ k_un, float* __restrict__ tmax) {
  __shared__ float kb[16][cDP];
  const int tid = threadIdx.x;
  const int m = tid & 63, h = tid >> 6, lane = tid & 63;
  float pr[16];
#pragma unroll
  for (int d = 0; d < 16; ++d) pr[d] = proj[m * 16 + d];
  for (int g = blockIdx.x; g < ROWS_KV / 16; g += gridDim.x) {
    const int r0 = g * 16;
    __syncthreads();
    for (int i = tid; i < 16 * cDP; i += 512)
      kb[i >> 7][i & 127] = kbuf[(size_t)(r0 + (i >> 7)) * cDP + (i & 127)];
    __syncthreads();
    for (int r = 0; r < 16; ++r) {
      int row = r0 + r;
      int b = row / cNCTX;
      int t = row - b * cNCTX;
      float4 q0 = *(const float4*)&kb[r][h * 16 + 0];
      float4 q1 = *(const float4*)&kb[r][h * 16 + 4];
      float4 q2 = *(const float4*)&kb[r][h * 16 + 8];
      float4 q3 = *(const float4*)&kb[r][h * 16 + 12];
      float dash = q0.x * pr[0] + q0.y * pr[1] + q0.z * pr[2] + q0.w * pr[3]
                 + q1.x * pr[4] + q1.y * pr[5] + q1.z * pr[6] + q1.w * pr[7]
                 + q2.x * pr[8] + q2.y * pr[9] + q2.z * pr[10] + q2.w * pr[11]
                 + q3.x * pr[12] + q3.y * pr[13] + q3.z * pr[14] + q3.w * pr[15];
      dash *= 0.5f;
      float ss = q0.x * q0.x + q0.y * q0.y + q0.z * q0.z + q0.w * q0.w
               + q1.x * q1.x + q1.y * q1.y + q1.z * q1.z + q1.w * q1.w
               + q2.x * q2.x + q2.y * q2.y + q2.z * q2.z + q2.w * q2.w
               + q3.x * q3.x + q3.y * q3.y + q3.z * q3.z + q3.w * q3.w;
      float un = cRATIO * __expf(dash - 0.125f * ss);
      if (t < cNQ)
        k_un[((size_t)(b * cH + h) * cNQ + t) * cM + m] = un;
      if (t >= cSHIFT)
        k_un[((size_t)((b + cB) * cH + h) * cNQ + (t - cSHIFT)) * cM + m] = un;
      float mx = wmax64(dash);
      if (lane == 0) tmax[(b * cH + h) * cNCTX + t] = mx;
    }
  }
}

// ============ K4b: windowed max (R18 exact) ============
__global__ __launch_bounds__(256) void k4b_mxk(
    const float* __restrict__ tmax, float* __restrict__ mxk) {
  const int bh = blockIdx.x;
  const int tid = threadIdx.x;
  float m0 = -1e30f, m1 = -1e30f;
  for (int t = tid; t < cNCTX; t += 256) {
    float v = tmax[bh * cNCTX + t];
    if (t < cNQ) m0 = fmaxf(m0, v);
    if (t >= cSHIFT) m1 = fmaxf(m1, v);
  }
  __shared__ float s0[256], s1[256];
  s0[tid] = m0; s1[tid] = m1;
  __syncthreads();
  for (int s = 128; s; s >>= 1) {
    if (tid < s) { s0[tid] = fmaxf(s0[tid], s0[tid + s]); s1[tid] = fmaxf(s1[tid], s1[tid + s]); }
    __syncthreads();
  }
  if (tid == 0) { mxk[bh] = s0[0]; mxk[bh + 128] = s1[0]; }
}

// ============ K5a: partial ctx/ksum over 512-token chunks (R18 exact) ============
__global__ __launch_bounds__(256) void k5a_ctx(
    const float* __restrict__ k_un, const float* __restrict__ vbuf,
    const float* __restrict__ mxk,
    float* __restrict__ part_c, float* __restrict__ part_k) {
  const int bbh = blockIdx.x;   // 0..255
  const int ch = blockIdx.y;    // 0..5
  const int bb = bbh >> 3, h = bbh & 7;
  const int b = bb & 15, toff = (bb >> 4) * cSHIFT;
  const float ek = expf(-mxk[bbh]);
  const int tid = threadIdx.x, m = tid & 63, eq = tid >> 6;
  __shared__ float ub[64][64];
  __shared__ float vb[64][16];
  float c0 = 0, c1 = 0, c2 = 0, c3 = 0, ks = 0;
  const int nb = ch * 512;
  for (int n0 = nb; n0 < nb + 512; n0 += 64) {
    for (int i = tid; i < 64 * 64; i += 256)
      ub[i >> 6][i & 63] = k_un[((size_t)bbh * cNQ + n0 + (i >> 6)) * cM + (i & 63)];
    for (int i = tid; i < 64 * 16; i += 256)
      vb[i >> 4][i & 15] = vbuf[((size_t)(b * cNCTX) + toff + n0 + (i >> 4)) * cDP + h * 16 + (i & 15)];
    __syncthreads();
#pragma unroll 4
    for (int nn = 0; nn < 64; ++nn) {
      float kf = ub[nn][m] * ek + cEPST;
      ks += kf;
      float4 vv = *(const float4*)&vb[nn][eq * 4];
      c0 += kf * vv.x; c1 += kf * vv.y; c2 += kf * vv.z; c3 += kf * vv.w;
    }
    __syncthreads();
  }
  size_t po = (size_t)ch * 256 + bbh;
  part_c[po * 1024 + m * 16 + eq * 4 + 0] = c0;
  part_c[po * 1024 + m * 16 + eq * 4 + 1] = c1;
  part_c[po * 1024 + m * 16 + eq * 4 + 2] = c2;
  part_c[po * 1024 + m * 16 + eq * 4 + 3] = c3;
  if (eq == 0) part_k[po * 64 + m] = ks;
}

__global__ __launch_bounds__(256) void k5a2_red(
    const float* __restrict__ part_c, const float* __restrict__ part_k,
    float* __restrict__ ctx2, float* __restrict__ ksum) {
  const int bbh = blockIdx.x;
  const int tid = threadIdx.x;
  for (int i = tid; i < 1024; i += 256) {
    float s = 0;
#pragma unroll
    for (int ch = 0; ch < 6; ++ch) s += part_c[((size_t)ch * 256 + bbh) * 1024 + i];
    ctx2[bbh * 1024 + i] = s;
  }
  if (tid < 64) {
    float s = 0;
#pragma unroll
    for (int ch = 0; ch < 6; ++ch) s += part_k[((size_t)ch * 256 + bbh) * 64 + tid];
    ksum[bbh * cM + tid] = s;
  }
}

// ============ KQ2 (512 threads): LN1(f16) -> fdot2 qGEMM -> FAVOR (paired, ss amortized) -> MFMA PV ============
// R18 structure; ss computed once per row (lane L owns row L&31, identical fp32 op order)
// and broadcast via __shfl. All outputs bit-identical to R18.
__global__ __launch_bounds__(512, 4) void kq_fused2(
    const float* __restrict__ y1,
    const float* __restrict__ ln1w, const float* __restrict__ ln1b,
    const unsigned short* __restrict__ wqT, const float* __restrict__ proj,
    const float* __restrict__ ctx2, const float* __restrict__ ksum,
    float* __restrict__ q_un, float* __restrict__ attn) {
  __shared__ unsigned short wqs[128 * 128];   // 32KB fp16
  __shared__ unsigned short xb[32 * 128];     // 8KB fp16
  __shared__ float qb[32][132];               // 16.9KB
  __shared__ unsigned short qfl[8][16][72];   // 18KB bf16 qf/den [wave][row][m]
  const int tid = threadIdx.x;
  const int bb = blockIdx.y;                  // 0..31
  {
    const uint4* s1 = (const uint4*)wqT; uint4* d1 = (uint4*)wqs;
    for (int i = tid; i < 2048; i += 512) d1[i] = s1[i];
  }
  const int lane = tid & 63, wvid = tid >> 6;   // 8 waves
  const int lrow = tid >> 4, c8 = tid & 15;     // LN: 32 rows x 16 chunks of 8
  const int cx = tid & 31, ry2 = tid >> 5;      // GEMM: rows ry2*2..+1, cols cx+32*cc
  const int m = lane;
  const int h = wvid;                           // head per wave
  float pr[16];
#pragma unroll
  for (int d = 0; d < 16; ++d) pr[d] = proj[m * 16 + d];
  // ctx2 B-frags (bf16, PV only) + ksum scalar
  short8 bfr[2];
  {
    const float* cp = ctx2 + (size_t)(bb * cH + h) * 1024;
#pragma unroll
    for (int kh = 0; kh < 2; ++kh) {
      short8 bfv;
#pragma unroll
      for (int j = 0; j < 8; ++j) {
        int mm = kh * 32 + (lane >> 4) * 8 + j;
        ((unsigned short*)&bfv)[j] = (unsigned short)bf16r(cp[mm * 16 + (lane & 15)]);
      }
      bfr[kh] = bfv;
    }
  }
  const float kslr = ksum[(bb * cH + h) * cM + lane];
  float lw[8], lb[8];
  *(float4*)&lw[0] = *(const float4*)(ln1w + c8 * 8 + 0);
  *(float4*)&lw[4] = *(const float4*)(ln1w + c8 * 8 + 4);
  *(float4*)&lb[0] = *(const float4*)(ln1b + c8 * 8 + 0);
  *(float4*)&lb[4] = *(const float4*)(ln1b + c8 * 8 + 4);
  uint4* xb4 = (uint4*)xb;
  const uint4* wq4 = (const uint4*)wqs;
  __syncthreads();

  for (int tile = blockIdx.x; tile < 96; tile += 16) {
    const int n0 = tile * 32;
    const size_t r0g = (size_t)bb * cNQ + n0;
    {  // LN1 -> xb (fp16 swizzled); row lrow, cols c8*8..+7  (R18 exact)
      const float* yr = y1 + (r0g + lrow) * 128 + c8 * 8;
      float v[8];
      *(float4*)&v[0] = *(const float4*)(yr + 0);
      *(float4*)&v[4] = *(const float4*)(yr + 4);
      float s = 0.f, q = 0.f;
#pragma unroll
      for (int j = 0; j < 8; ++j) { s += v[j]; q += v[j] * v[j]; }
#pragma unroll
      for (int o = 1; o <= 8; o <<= 1) { s += __shfl_xor(s, o); q += __shfl_xor(q, o); }
      float mu = s * (1.0f / 128.0f);
      float rs = rsqrtf(q * (1.0f / 128.0f) - mu * mu + cLNEPS);
      unsigned int us[4];
#pragma unroll
      for (int j = 0; j < 4; ++j) {
        float f0 = (v[2 * j] - mu) * rs * lw[2 * j] + lb[2 * j];
        float f1 = (v[2 * j + 1] - mu) * rs * lw[2 * j + 1] + lb[2 * j + 1];
        us[j] = f16r(f0) | (f16r(f1) << 16);
      }
      xb4[lrow * 16 + (c8 ^ (lrow & 15))] = make_uint4(us[0], us[1], us[2], us[3]);
    }
    __syncthreads();
    {  // qGEMM via v_dot2_f32_f16 (R18 exact)
      float acc[2][4] = {};
#pragma unroll 2
      for (int kg = 0; kg < 16; ++kg) {
        uint4 xv[2], wv[4];
#pragma unroll
        for (int rr = 0; rr < 2; ++rr) {
          int r = ry2 * 2 + rr;
          xv[rr] = xb4[r * 16 + (kg ^ (r & 15))];
        }
#pragma unroll
        for (int cc = 0; cc < 4; ++cc) {
          int c = cx + 32 * cc;
          wv[cc] = wq4[c * 16 + (kg ^ (c & 15))];
        }
#pragma unroll
        for (int cc = 0; cc < 4; ++cc) {
          const half2* wh = (const half2*)&wv[cc];
#pragma unroll
          for (int rr = 0; rr < 2; ++rr) {
            const half2* xh = (const half2*)&xv[rr];
#pragma unroll
            for (int p = 0; p < 4; ++p)
              acc[rr][cc] = __builtin_amdgcn_fdot2(xh[p], wh[p], acc[rr][cc], false);
          }
        }
      }
#pragma unroll
      for (int rr = 0; rr < 2; ++rr)
#pragma unroll
        for (int cc = 0; cc < 4; ++cc)
          qb[ry2 * 2 + rr][cx + 32 * cc] = acc[rr][cc];
    }
    __syncthreads();
    // ss amortization: lane L computes ss for row (L&31), EXACT R18 op order (bit-identical)
    float ssv;
    {
      int r = lane & 31;
      float4 s0 = *(const float4*)&qb[r][h * 16 + 0];
      float4 s1 = *(const float4*)&qb[r][h * 16 + 4];
      float4 s2 = *(const float4*)&qb[r][h * 16 + 8];
      float4 s3 = *(const float4*)&qb[r][h * 16 + 12];
      ssv = s0.x * s0.x + s0.y * s0.y + s0.z * s0.z + s0.w * s0.w
          + s1.x * s1.x + s1.y * s1.y + s1.z * s1.z + s1.w * s1.w
          + s2.x * s2.x + s2.y * s2.y + s2.z * s2.z + s2.w * s2.w
          + s3.x * s3.x + s3.y * s3.y + s3.z * s3.z + s3.w * s3.w;
    }
    // FAVOR: rows in PAIRS with interleaved reduction chains (R18 exact math).
#pragma unroll
    for (int half = 0; half < 2; ++half) {
      for (int rr = 0; rr < 16; rr += 2) {
        const int rA = half * 16 + rr, rB = rA + 1;
        float4 a0 = *(const float4*)&qb[rA][h * 16 + 0];
        float4 a1 = *(const float4*)&qb[rA][h * 16 + 4];
        float4 a2 = *(const float4*)&qb[rA][h * 16 + 8];
        float4 a3 = *(const float4*)&qb[rA][h * 16 + 12];
        float4 b0 = *(const float4*)&qb[rB][h * 16 + 0];
        float4 b1 = *(const float4*)&qb[rB][h * 16 + 4];
        float4 b2 = *(const float4*)&qb[rB][h * 16 + 8];
        float4 b3 = *(const float4*)&qb[rB][h * 16 + 12];
        float dashA = a0.x * pr[0] + a0.y * pr[1] + a0.z * pr[2] + a0.w * pr[3]
                    + a1.x * pr[4] + a1.y * pr[5] + a1.z * pr[6] + a1.w * pr[7]
                    + a2.x * pr[8] + a2.y * pr[9] + a2.z * pr[10] + a2.w * pr[11]
                    + a3.x * pr[12] + a3.y * pr[13] + a3.z * pr[14] + a3.w * pr[15];
        float dashB = b0.x * pr[0] + b0.y * pr[1] + b0.z * pr[2] + b0.w * pr[3]
                    + b1.x * pr[4] + b1.y * pr[5] + b1.z * pr[6] + b1.w * pr[7]
                    + b2.x * pr[8] + b2.y * pr[9] + b2.z * pr[10] + b2.w * pr[11]
                    + b3.x * pr[12] + b3.y * pr[13] + b3.z * pr[14] + b3.w * pr[15];
        dashA *= 0.5f;
        dashB *= 0.5f;
        float ssA = __shfl(ssv, rA);
        float ssB = __shfl(ssv, rB);
        float unA = cRATIO * __expf(dashA - 0.125f * ssA);
        float unB = cRATIO * __expf(dashB - 0.125f * ssB);
        size_t baseA = (size_t)(bb * cH + h) * cNQ + n0 + rA;
        size_t baseB = baseA + 1;
        q_un[baseA * cM + m] = unA;
        q_un[baseB * cM + m] = unB;
        float mA = dashA, mB = dashB;
#pragma unroll
        for (int o = 32; o; o >>= 1) {
          float tA = __shfl_xor(mA, o);
          float tB = __shfl_xor(mB, o);
          mA = fmaxf(mA, tA);
          mB = fmaxf(mB, tB);
        }
        float qfA = unA * __expf(-mA) + cEPST;
        float qfB = unB * __expf(-mB) + cEPST;
        float dA = qfA * kslr, dB = qfB * kslr;
#pragma unroll
        for (int o = 32; o; o >>= 1) {
          float tA = __shfl_xor(dA, o);
          float tB = __shfl_xor(dB, o);
          dA += tA;
          dB += tB;
        }
        float ivA = 1.0f / dA, ivB = 1.0f / dB;
        qfl[wvid][rr][lane] = (unsigned short)bf16r(qfA * ivA);
        qfl[wvid][rr + 1][lane] = (unsigned short)bf16r(qfB * ivB);
      }
      // PV: attn = (qf/den) @ ctx2 directly; wave-synchronous
      {
        const unsigned short* qp = &qfl[wvid][0][0];
        int ab = (lane & 15) * 72 + (lane >> 4) * 8;
        short8 a0 = *(const short8*)&qp[ab];
        short8 a1 = *(const short8*)&qp[ab + 32];
        f32x4 c = {0.f, 0.f, 0.f, 0.f};
        c = MFMA16x16(a0, bfr[0], c);
        c = MFMA16x16(a1, bfr[1], c);
#pragma unroll
        for (int reg = 0; reg < 4; ++reg) {
          int rloc = (lane >> 4) * 4 + reg;
          attn[(r0g + half * 16 + rloc) * cDP + h * 16 + (lane & 15)] = c[reg];
        }
      }
    }
    __syncthreads();
  }
}

// ============ K6: yout = y1 + attn @ wo.T + wo_b, MFMA (R18 exact) ============
__global__ __launch_bounds__(256, 2) void k6_wo(
    const float* __restrict__ attn,
    const unsigned short* __restrict__ woT, const float* __restrict__ wob,
    const float* __restrict__ y1, float* __restrict__ yout) {
  __shared__ unsigned short wos[16384];
  __shared__ unsigned short xb[4096];
  const int tid = threadIdx.x;
  {
    const uint4* s1 = (const uint4*)woT; uint4* d1 = (uint4*)wos;
    for (int i = tid; i < 2048; i += 256) d1[i] = s1[i];
  }
  const int lane = tid & 63, wv = tid >> 6;
  const int lrow = tid >> 3, lsub = tid & 7;
  const int colbase = wv * 32;
  float wb[2];
#pragma unroll
  for (int ct = 0; ct < 2; ++ct) wb[ct] = wob[colbase + ct * 16 + (lane & 15)];
  uint4* xb4 = (uint4*)xb;
  __syncthreads();
  for (int g = blockIdx.x; g < ROWS_Q / 32; g += gridDim.x) {
    const int r0 = g * 32;
    {  // stage attn tile -> bf16 swizzled
      const float* ar = attn + (size_t)(r0 + lrow) * 128 + lsub * 16;
      float v[16];
      *(float4*)&v[0] = *(const float4*)(ar + 0);
      *(float4*)&v[4] = *(const float4*)(ar + 4);
      *(float4*)&v[8] = *(const float4*)(ar + 8);
      *(float4*)&v[12] = *(const float4*)(ar + 12);
      unsigned int us[8];
#pragma unroll
      for (int j = 0; j < 8; ++j)
        us[j] = bf16r(v[2 * j]) | (bf16r(v[2 * j + 1]) << 16);
      int s0 = (lsub * 2) ^ (lrow & 15), s1 = (lsub * 2 + 1) ^ (lrow & 15);
      xb4[lrow * 16 + s0] = make_uint4(us[0], us[1], us[2], us[3]);
      xb4[lrow * 16 + s1] = make_uint4(us[4], us[5], us[6], us[7]);
    }
    __syncthreads();
    {
      f32x4 acc[2][2] = {{{0.f,0.f,0.f,0.f},{0.f,0.f,0.f,0.f}},
                         {{0.f,0.f,0.f,0.f},{0.f,0.f,0.f,0.f}}};
#pragma unroll
      for (int kc = 0; kc < 4; ++kc) {
        short8 af[2], bfv[2];
#pragma unroll
        for (int rt = 0; rt < 2; ++rt) {
          int row = rt * 16 + (lane & 15);
          int slot = ((lane >> 4) + kc * 4) ^ (row & 15);
          af[rt] = *(const short8*)&xb[row * 128 + slot * 8];
        }
#pragma unroll
        for (int ct = 0; ct < 2; ++ct) {
          int col = colbase + ct * 16 + (lane & 15);
          int slot = ((lane >> 4) + kc * 4) ^ (col & 15);
          bfv[ct] = *(const short8*)&wos[col * 128 + slot * 8];
        }
#pragma unroll
        for (int rt = 0; rt < 2; ++rt)
#pragma unroll
          for (int ct = 0; ct < 2; ++ct)
            acc[rt][ct] = MFMA16x16(af[rt], bfv[ct], acc[rt][ct]);
      }
#pragma unroll
      for (int rt = 0; rt < 2; ++rt)
#pragma unroll
        for (int ct = 0; ct < 2; ++ct) {
          int col = colbase + ct * 16 + (lane & 15);
#pragma unroll
          for (int reg = 0; reg < 4; ++reg) {
            int row = rt * 16 + (lane >> 4) * 4 + reg;
            size_t o = (size_t)(r0 + row) * 128 + col;
            yout[o] = acc[rt][ct][reg] + wb[ct] + y1[o];
          }
        }
    }
    __syncthreads();
  }
}

// =============================== launch ===============================
extern "C" void kernel_launch(void* const* d_in, const int* in_sizes, int n_in,
                              void* d_out, int out_size, void* d_ws, size_t ws_size,
                              hipStream_t stream) {
  (void)in_sizes; (void)n_in; (void)out_size; (void)ws_size;
  const float* x = (const float*)d_in[0];
  const float* y = (const float*)d_in[1];
  const float* proj = (const float*)d_in[2];
  const float* ln1w = (const float*)d_in[3];
  const float* ln1b = (const float*)d_in[4];
  const float* ln2w = (const float*)d_in[5];
  const float* ln2b = (const float*)d_in[6];
  const float* ln4w = (const float*)d_in[7];
  const float* ln4b = (const float*)d_in[8];
  const float* fcw = (const float*)d_in[9];
  const float* fcb = (const float*)d_in[10];
  const float* prw = (const float*)d_in[11];
  const float* prb = (const float*)d_in[12];
  const float* wq = (const float*)d_in[13];
  const float* wk = (const float*)d_in[14];
  const float* wv = (const float*)d_in[15];
  const float* wo = (const float*)d_in[16];
  const float* wob = (const float*)d_in[17];

  float* out = (float*)d_out;
  float* q_un = out + 12582912;
  float* k_un = out + 62914560;

  float* ws = (float*)d_ws;
  float* y1 = ws;                          // 12,582,912
  float* kbuf = ws + 12582912;             // 6,553,600 (dead after k4)
  float* vbuf = ws + 19136512;             // 6,553,600 (dead after k5a)
  float* part_c = ws + 12582912;           // 1,572,864 (aliases kbuf; after k4)
  float* part_k = ws + 14155776;           // 98,304
  float* attn = ws + 12582912;             // 12,582,912 (aliases kbuf+vbuf; after k5a2)
  float* tmax = ws + 26476544;             // 409,600
  float* mxk = ws + 26886144;              // 256
  float* ksum = ws + 26886400;             // 16,384
  float* ctx2 = ws + 26902784;             // 262,144
  unsigned short* fcT = (unsigned short*)(ws + 27164928);   // 4 x 16384 ushorts
  unsigned short* prT = fcT + 16384;
  unsigned short* wqT = prT + 16384;
  unsigned short* woT = wqT + 16384;

  k0_prep<<<dim3(4), dim3(256), 0, stream>>>(fcw, prw, wq, wo, fcT, prT, wqT, woT);
  k1_mlp<<<dim3(512), dim3(256), 0, stream>>>(y, ln4w, ln4b, fcT, fcb, prT, prb, y1);
  k2_kv<<<dim3(400), dim3(512), 0, stream>>>(x, ln2w, ln2b, wk, wv, kbuf, vbuf);
  k4_kun<<<dim3(400), dim3(512), 0, stream>>>(kbuf, proj, k_un, tmax);
  k4b_mxk<<<dim3(128), dim3(256), 0, stream>>>(tmax, mxk);
  k5a_ctx<<<dim3(256, 6), dim3(256), 0, stream>>>(k_un, vbuf, mxk, part_c, part_k);
  k5a2_red<<<dim3(256), dim3(256), 0, stream>>>(part_c, part_k, ctx2, ksum);
  kq_fused2<<<dim3(16, 32), dim3(512), 0, stream>>>(y1, ln1w, ln1b, wqT, proj,
                                                    ctx2, ksum, q_un, attn);
  k6_wo<<<dim3(512), dim3(256), 0, stream>>>(attn, woT, wob, y1, out);
}

// Round 20
// 406.135 us; speedup vs baseline: 1.0944x; 1.0944x over previous
//
#include <hip/hip_runtime.h>
#include <math.h>

// ---------------- problem constants ----------------
constexpr int cH = 8;
constexpr int cDP = 128;
constexpr int cM = 64;
constexpr int cB = 16;
constexpr int cNCTX = 3200;
constexpr int cNQ = 3072;
constexpr int cSHIFT = 128;
constexpr int ROWS_Q = 2 * cB * cNQ;    // 98304
constexpr int ROWS_KV = cB * cNCTX;     // 51200
constexpr float cRATIO = 0.125f;
constexpr float cEPST = 0.125e-4f;
constexpr float cLNEPS = 1e-5f;

typedef float f32x4 __attribute__((ext_vector_type(4)));
typedef short short8 __attribute__((ext_vector_type(8)));
typedef _Float16 half2 __attribute__((ext_vector_type(2)));

#define MFMA16x16(a, b, c) __builtin_amdgcn_mfma_f32_16x16x32_bf16((a), (b), (c), 0, 0, 0)

__device__ __forceinline__ float wmax64(float v) {
#pragma unroll
  for (int o = 32; o; o >>= 1) v = fmaxf(v, __shfl_xor(v, o));
  return v;
}
__device__ __forceinline__ float wsum64(float v) {
#pragma unroll
  for (int o = 32; o; o >>= 1) v += __shfl_xor(v, o);
  return v;
}
__device__ __forceinline__ float gelu_f(float x) {
  return 0.5f * x * (1.0f + tanhf(0.79788456080286536f * (x + 0.044715f * x * x * x)));
}
// fp32 -> bf16 (RTNE), low 16 bits
__device__ __forceinline__ unsigned int bf16r(float f) {
  unsigned int x = __float_as_uint(f);
  return (x + 0x7fffu + ((x >> 16) & 1u)) >> 16;
}
// fp32 -> fp16 (RTNE), low 16 bits
__device__ __forceinline__ unsigned int f16r(float f) {
  _Float16 hh = (_Float16)f;
  unsigned short u;
  __builtin_memcpy(&u, &hh, 2);
  return (unsigned int)u;
}
// 8 packed bf16 (uint4) -> 8 floats
__device__ __forceinline__ void cvt8(uint4 u, float f[8]) {
  f[0] = __uint_as_float(u.x << 16);
  f[1] = __uint_as_float(u.x & 0xffff0000u);
  f[2] = __uint_as_float(u.y << 16);
  f[3] = __uint_as_float(u.y & 0xffff0000u);
  f[4] = __uint_as_float(u.z << 16);
  f[5] = __uint_as_float(u.z & 0xffff0000u);
  f[6] = __uint_as_float(u.w << 16);
  f[7] = __uint_as_float(u.w & 0xffff0000u);
}
// swizzled ushort index for element (row, k) in a [*][128] 16-bit tile
__device__ __forceinline__ int swz(int row, int k) {
  return row * 128 + ((((k >> 3) ^ (row & 15)) << 3) | (k & 7));
}

// ============ K0: weight prep -> 16-bit, [n][k] layout, pre-swizzled (R19 exact) ============
__global__ __launch_bounds__(256) void k0_prep(
    const float* __restrict__ fcw, const float* __restrict__ prw,
    const float* __restrict__ wq, const float* __restrict__ wo,
    unsigned short* __restrict__ fcT, unsigned short* __restrict__ prT,
    unsigned short* __restrict__ wqT, unsigned short* __restrict__ woT) {
  const int mat = blockIdx.x;
  const float* src = mat == 0 ? fcw : mat == 1 ? prw : mat == 2 ? wq : wo;
  unsigned short* dst = mat == 0 ? fcT : mat == 1 ? prT : mat == 2 ? wqT : woT;
  const bool tr = (mat < 2);   // fc_w/pr_w are [k][n]; wq/wo are [n][k]
  for (int i = threadIdx.x; i < 16384; i += 256) {
    int n = i >> 7, k = i & 127;
    float f = tr ? src[k * 128 + n] : src[i];
    dst[swz(n, k)] = (unsigned short)(mat == 2 ? f16r(f) : bf16r(f));
  }
}

// ============ K1: MLP (LN4 -> fc -> gelu -> pr -> +y), MFMA, 256 threads (R19 exact) ============
__global__ __launch_bounds__(256, 2) void k1_mlp(
    const float* __restrict__ y,
    const float* __restrict__ ln4w, const float* __restrict__ ln4b,
    const unsigned short* __restrict__ fcT, const float* __restrict__ fcb,
    const unsigned short* __restrict__ prT, const float* __restrict__ prb,
    float* __restrict__ y1) {
  __shared__ unsigned short wfc[16384];
  __shared__ unsigned short wpr[16384];
  __shared__ unsigned short xb[4096];
  __shared__ unsigned short hb[4096];
  const int tid = threadIdx.x;
  {
    const uint4* s1 = (const uint4*)fcT; uint4* d1 = (uint4*)wfc;
    const uint4* s2 = (const uint4*)prT; uint4* d2 = (uint4*)wpr;
    for (int i = tid; i < 2048; i += 256) { d1[i] = s1[i]; d2[i] = s2[i]; }
  }
  const int lane = tid & 63, wv = tid >> 6;
  const int lrow = tid >> 3, lsub = tid & 7;
  const int colbase = wv * 32;
  float fb[2], pb[2];
#pragma unroll
  for (int ct = 0; ct < 2; ++ct) {
    int col = colbase + ct * 16 + (lane & 15);
    fb[ct] = fcb[col];
    pb[ct] = prb[col];
  }
  float lw[16], lb[16];
  *(float4*)&lw[0] = *(const float4*)(ln4w + lsub * 16 + 0);
  *(float4*)&lw[4] = *(const float4*)(ln4w + lsub * 16 + 4);
  *(float4*)&lw[8] = *(const float4*)(ln4w + lsub * 16 + 8);
  *(float4*)&lw[12] = *(const float4*)(ln4w + lsub * 16 + 12);
  *(float4*)&lb[0] = *(const float4*)(ln4b + lsub * 16 + 0);
  *(float4*)&lb[4] = *(const float4*)(ln4b + lsub * 16 + 4);
  *(float4*)&lb[8] = *(const float4*)(ln4b + lsub * 16 + 8);
  *(float4*)&lb[12] = *(const float4*)(ln4b + lsub * 16 + 12);
  uint4* xb4 = (uint4*)xb;
  __syncthreads();

  for (int g = blockIdx.x; g < ROWS_Q / 32; g += gridDim.x) {
    const int r0 = g * 32;
    {  // LN4 -> xb (bf16 swizzled)
      const float* yr = y + (size_t)(r0 + lrow) * 128 + lsub * 16;
      float v[16];
      *(float4*)&v[0] = *(const float4*)(yr + 0);
      *(float4*)&v[4] = *(const float4*)(yr + 4);
      *(float4*)&v[8] = *(const float4*)(yr + 8);
      *(float4*)&v[12] = *(const float4*)(yr + 12);
      float s = 0.f, q = 0.f;
#pragma unroll
      for (int j = 0; j < 16; ++j) { s += v[j]; q += v[j] * v[j]; }
#pragma unroll
      for (int o = 1; o <= 4; o <<= 1) { s += __shfl_xor(s, o); q += __shfl_xor(q, o); }
      float mu = s * (1.0f / 128.0f);
      float rs = rsqrtf(q * (1.0f / 128.0f) - mu * mu + cLNEPS);
      unsigned int us[8];
#pragma unroll
      for (int j = 0; j < 8; ++j) {
        float f0 = (v[2 * j] - mu) * rs * lw[2 * j] + lb[2 * j];
        float f1 = (v[2 * j + 1] - mu) * rs * lw[2 * j + 1] + lb[2 * j + 1];
        us[j] = bf16r(f0) | (bf16r(f1) << 16);
      }
      int s0 = (lsub * 2) ^ (lrow & 15), s1 = (lsub * 2 + 1) ^ (lrow & 15);
      xb4[lrow * 16 + s0] = make_uint4(us[0], us[1], us[2], us[3]);
      xb4[lrow * 16 + s1] = make_uint4(us[4], us[5], us[6], us[7]);
    }
    __syncthreads();
    {  // GEMM1 (MFMA) + gelu -> hb
      f32x4 acc[2][2] = {{{0.f,0.f,0.f,0.f},{0.f,0.f,0.f,0.f}},
                         {{0.f,0.f,0.f,0.f},{0.f,0.f,0.f,0.f}}};
#pragma unroll
      for (int kc = 0; kc < 4; ++kc) {
        short8 af[2], bfv[2];
#pragma unroll
        for (int rt = 0; rt < 2; ++rt) {
          int row = rt * 16 + (lane & 15);
          int slot = ((lane >> 4) + kc * 4) ^ (row & 15);
          af[rt] = *(const short8*)&xb[row * 128 + slot * 8];
        }
#pragma unroll
        for (int ct = 0; ct < 2; ++ct) {
          int col = colbase + ct * 16 + (lane & 15);
          int slot = ((lane >> 4) + kc * 4) ^ (col & 15);
          bfv[ct] = *(const short8*)&wfc[col * 128 + slot * 8];
        }
#pragma unroll
        for (int rt = 0; rt < 2; ++rt)
#pragma unroll
          for (int ct = 0; ct < 2; ++ct)
            acc[rt][ct] = MFMA16x16(af[rt], bfv[ct], acc[rt][ct]);
      }
#pragma unroll
      for (int rt = 0; rt < 2; ++rt)
#pragma unroll
        for (int ct = 0; ct < 2; ++ct) {
          int col = colbase + ct * 16 + (lane & 15);
#pragma unroll
          for (int reg = 0; reg < 4; ++reg) {
            int row = rt * 16 + (lane >> 4) * 4 + reg;
            hb[swz(row, col)] = (unsigned short)bf16r(gelu_f(acc[rt][ct][reg] + fb[ct]));
          }
        }
    }
    __syncthreads();
    {  // GEMM2 (MFMA) + bias + residual -> y1
      f32x4 a2[2][2] = {{{0.f,0.f,0.f,0.f},{0.f,0.f,0.f,0.f}},
                        {{0.f,0.f,0.f,0.f},{0.f,0.f,0.f,0.f}}};
#pragma unroll
      for (int kc = 0; kc < 4; ++kc) {
        short8 af[2], bfv[2];
#pragma unroll
        for (int rt = 0; rt < 2; ++rt) {
          int row = rt * 16 + (lane & 15);
          int slot = ((lane >> 4) + kc * 4) ^ (row & 15);
          af[rt] = *(const short8*)&hb[row * 128 + slot * 8];
        }
#pragma unroll
        for (int ct = 0; ct < 2; ++ct) {
          int col = colbase + ct * 16 + (lane & 15);
          int slot = ((lane >> 4) + kc * 4) ^ (col & 15);
          bfv[ct] = *(const short8*)&wpr[col * 128 + slot * 8];
        }
#pragma unroll
        for (int rt = 0; rt < 2; ++rt)
#pragma unroll
          for (int ct = 0; ct < 2; ++ct)
            a2[rt][ct] = MFMA16x16(af[rt], bfv[ct], a2[rt][ct]);
      }
#pragma unroll
      for (int rt = 0; rt < 2; ++rt)
#pragma unroll
        for (int ct = 0; ct < 2; ++ct) {
          int col = colbase + ct * 16 + (lane & 15);
#pragma unroll
          for (int reg = 0; reg < 4; ++reg) {
            int row = rt * 16 + (lane >> 4) * 4 + reg;
            size_t o = (size_t)(r0 + row) * 128 + col;
            y1[o] = a2[rt][ct][reg] + pb[ct] + y[o];
          }
        }
    }
    __syncthreads();
  }
}

// ============ K2: LN2(x) -> k,v projections (R19 exact) ============
__global__ __launch_bounds__(512) void k2_kv(
    const float* __restrict__ x,
    const float* __restrict__ ln2w, const float* __restrict__ ln2b,
    const float* __restrict__ wkw, const float* __restrict__ wvw,
    float* __restrict__ kbuf, float* __restrict__ vbuf) {
  __shared__ float wkT[32 * cDP];
  __shared__ float wvT[32 * cDP];
  __shared__ float xbs[16][32];
  const int tid = threadIdx.x;
  for (int i = tid; i < 32 * cDP; i += 512) {
    int j = i >> 5, d = i & 31;
    wkT[d * cDP + j] = wkw[i];
    wvT[d * cDP + j] = wvw[i];
  }
  const int dl = tid & 31, rl = tid >> 5;
  const int col = tid & 127, rh = tid >> 7;
  const float l2w = ln2w[dl], l2b = ln2b[dl];
  __syncthreads();
  for (int g = blockIdx.x; g < ROWS_KV / 16; g += gridDim.x) {
    const int r0 = g * 16;
    __syncthreads();
    {
      float v = x[(size_t)(r0 + rl) * 32 + dl];
      float s = v, q = v * v;
#pragma unroll
      for (int o = 16; o; o >>= 1) { s += __shfl_xor(s, o); q += __shfl_xor(q, o); }
      float mu = s * (1.0f / 32.0f);
      float var = q * (1.0f / 32.0f) - mu * mu;
      xbs[rl][dl] = (v - mu) * rsqrtf(var + cLNEPS) * l2w + l2b;
    }
    __syncthreads();
    float ak0 = 0, ak1 = 0, ak2 = 0, ak3 = 0, av0 = 0, av1 = 0, av2 = 0, av3 = 0;
    for (int d = 0; d < 32; d += 4) {
      float4 v0 = *(const float4*)&xbs[rh * 4 + 0][d];
      float4 v1 = *(const float4*)&xbs[rh * 4 + 1][d];
      float4 v2 = *(const float4*)&xbs[rh * 4 + 2][d];
      float4 v3 = *(const float4*)&xbs[rh * 4 + 3][d];
      float k0 = wkT[(d + 0) * cDP + col], k1 = wkT[(d + 1) * cDP + col];
      float k2 = wkT[(d + 2) * cDP + col], k3 = wkT[(d + 3) * cDP + col];
      float u0 = wvT[(d + 0) * cDP + col], u1 = wvT[(d + 1) * cDP + col];
      float u2 = wvT[(d + 2) * cDP + col], u3 = wvT[(d + 3) * cDP + col];
      ak0 += v0.x * k0 + v0.y * k1 + v0.z * k2 + v0.w * k3;
      ak1 += v1.x * k0 + v1.y * k1 + v1.z * k2 + v1.w * k3;
      ak2 += v2.x * k0 + v2.y * k1 + v2.z * k2 + v2.w * k3;
      ak3 += v3.x * k0 + v3.y * k1 + v3.z * k2 + v3.w * k3;
      av0 += v0.x * u0 + v0.y * u1 + v0.z * u2 + v0.w * u3;
      av1 += v1.x * u0 + v1.y * u1 + v1.z * u2 + v1.w * u3;
      av2 += v2.x * u0 + v2.y * u1 + v2.z * u2 + v2.w * u3;
      av3 += v3.x * u0 + v3.y * u1 + v3.z * u2 + v3.w * u3;
    }
    kbuf[(size_t)(r0 + rh * 4 + 0) * cDP + col] = ak0;
    kbuf[(size_t)(r0 + rh * 4 + 1) * cDP + col] = ak1;
    kbuf[(size_t)(r0 + rh * 4 + 2) * cDP + col] = ak2;
    kbuf[(size_t)(r0 + rh * 4 + 3) * cDP + col] = ak3;
    vbuf[(size_t)(r0 + rh * 4 + 0) * cDP + col] = av0;
    vbuf[(size_t)(r0 + rh * 4 + 1) * cDP + col] = av1;
    vbuf[(size_t)(r0 + rh * 4 + 2) * cDP + col] = av2;
    vbuf[(size_t)(r0 + rh * 4 + 3) * cDP + col] = av3;
  }
}

// ============ K4: k features + temporal-split windowed writes (R19 exact) ============
__global__ __launch_bounds__(512) void k4_kun(
    const float* __restrict__ kbuf, const float* __restrict__ proj,
    float* __restrict__ k_un, float* __restrict__ tmax) {
  __shared__ float kb[16][cDP];
  const int tid = threadIdx.x;
  const int m = tid & 63, h = tid >> 6, lane = tid & 63;
  float pr[16];
#pragma unroll
  for (int d = 0; d < 16; ++d) pr[d] = proj[m * 16 + d];
  for (int g = blockIdx.x; g < ROWS_KV / 16; g += gridDim.x) {
    const int r0 = g * 16;
    __syncthreads();
    for (int i = tid; i < 16 * cDP; i += 512)
      kb[i >> 7][i & 127] = kbuf[(size_t)(r0 + (i >> 7)) * cDP + (i & 127)];
    __syncthreads();
    for (int r = 0; r < 16; ++r) {
      int row = r0 + r;
      int b = row / cNCTX;
      int t = row - b * cNCTX;
      float4 q0 = *(const float4*)&kb[r][h * 16 + 0];
      float4 q1 = *(const float4*)&kb[r][h * 16 + 4];
      float4 q2 = *(const float4*)&kb[r][h * 16 + 8];
      float4 q3 = *(const float4*)&kb[r][h * 16 + 12];
      float dash = q0.x * pr[0] + q0.y * pr[1] + q0.z * pr[2] + q0.w * pr[3]
                 + q1.x * pr[4] + q1.y * pr[5] + q1.z * pr[6] + q1.w * pr[7]
                 + q2.x * pr[8] + q2.y * pr[9] + q2.z * pr[10] + q2.w * pr[11]
                 + q3.x * pr[12] + q3.y * pr[13] + q3.z * pr[14] + q3.w * pr[15];
      dash *= 0.5f;
      float ss = q0.x * q0.x + q0.y * q0.y + q0.z * q0.z + q0.w * q0.w
               + q1.x * q1.x + q1.y * q1.y + q1.z * q1.z + q1.w * q1.w
               + q2.x * q2.x + q2.y * q2.y + q2.z * q2.z + q2.w * q2.w
               + q3.x * q3.x + q3.y * q3.y + q3.z * q3.z + q3.w * q3.w;
      float un = cRATIO * __expf(dash - 0.125f * ss);
      if (t < cNQ)
        k_un[((size_t)(b * cH + h) * cNQ + t) * cM + m] = un;
      if (t >= cSHIFT)
        k_un[((size_t)((b + cB) * cH + h) * cNQ + (t - cSHIFT)) * cM + m] = un;
      float mx = wmax64(dash);
      if (lane == 0) tmax[(b * cH + h) * cNCTX + t] = mx;
    }
  }
}

// ============ K4b: windowed max (R19 exact) ============
__global__ __launch_bounds__(256) void k4b_mxk(
    const float* __restrict__ tmax, float* __restrict__ mxk) {
  const int bh = blockIdx.x;
  const int tid = threadIdx.x;
  float m0 = -1e30f, m1 = -1e30f;
  for (int t = tid; t < cNCTX; t += 256) {
    float v = tmax[bh * cNCTX + t];
    if (t < cNQ) m0 = fmaxf(m0, v);
    if (t >= cSHIFT) m1 = fmaxf(m1, v);
  }
  __shared__ float s0[256], s1[256];
  s0[tid] = m0; s1[tid] = m1;
  __syncthreads();
  for (int s = 128; s; s >>= 1) {
    if (tid < s) { s0[tid] = fmaxf(s0[tid], s0[tid + s]); s1[tid] = fmaxf(s1[tid], s1[tid + s]); }
    __syncthreads();
  }
  if (tid == 0) { mxk[bh] = s0[0]; mxk[bh + 128] = s1[0]; }
}

// ============ K5a: partial ctx/ksum over 512-token chunks (R19 exact) ============
__global__ __launch_bounds__(256) void k5a_ctx(
    const float* __restrict__ k_un, const float* __restrict__ vbuf,
    const float* __restrict__ mxk,
    float* __restrict__ part_c, float* __restrict__ part_k) {
  const int bbh = blockIdx.x;   // 0..255
  const int ch = blockIdx.y;    // 0..5
  const int bb = bbh >> 3, h = bbh & 7;
  const int b = bb & 15, toff = (bb >> 4) * cSHIFT;
  const float ek = expf(-mxk[bbh]);
  const int tid = threadIdx.x, m = tid & 63, eq = tid >> 6;
  __shared__ float ub[64][64];
  __shared__ float vb[64][16];
  float c0 = 0, c1 = 0, c2 = 0, c3 = 0, ks = 0;
  const int nb = ch * 512;
  for (int n0 = nb; n0 < nb + 512; n0 += 64) {
    for (int i = tid; i < 64 * 64; i += 256)
      ub[i >> 6][i & 63] = k_un[((size_t)bbh * cNQ + n0 + (i >> 6)) * cM + (i & 63)];
    for (int i = tid; i < 64 * 16; i += 256)
      vb[i >> 4][i & 15] = vbuf[((size_t)(b * cNCTX) + toff + n0 + (i >> 4)) * cDP + h * 16 + (i & 15)];
    __syncthreads();
#pragma unroll 4
    for (int nn = 0; nn < 64; ++nn) {
      float kf = ub[nn][m] * ek + cEPST;
      ks += kf;
      float4 vv = *(const float4*)&vb[nn][eq * 4];
      c0 += kf * vv.x; c1 += kf * vv.y; c2 += kf * vv.z; c3 += kf * vv.w;
    }
    __syncthreads();
  }
  size_t po = (size_t)ch * 256 + bbh;
  part_c[po * 1024 + m * 16 + eq * 4 + 0] = c0;
  part_c[po * 1024 + m * 16 + eq * 4 + 1] = c1;
  part_c[po * 1024 + m * 16 + eq * 4 + 2] = c2;
  part_c[po * 1024 + m * 16 + eq * 4 + 3] = c3;
  if (eq == 0) part_k[po * 64 + m] = ks;
}

__global__ __launch_bounds__(256) void k5a2_red(
    const float* __restrict__ part_c, const float* __restrict__ part_k,
    float* __restrict__ ctx2, float* __restrict__ ksum) {
  const int bbh = blockIdx.x;
  const int tid = threadIdx.x;
  for (int i = tid; i < 1024; i += 256) {
    float s = 0;
#pragma unroll
    for (int ch = 0; ch < 6; ++ch) s += part_c[((size_t)ch * 256 + bbh) * 1024 + i];
    ctx2[bbh * 1024 + i] = s;
  }
  if (tid < 64) {
    float s = 0;
#pragma unroll
    for (int ch = 0; ch < 6; ++ch) s += part_k[((size_t)ch * 256 + bbh) * 64 + tid];
    ksum[bbh * cM + tid] = s;
  }
}

// ============ KQ2 (512 threads): LN1(f16) -> fdot2 qGEMM -> FAVOR (paired max) -> MFMA denom + PV ============
// R19 structure; sum-reduction chains replaced by MFMA denominator (R14/R15-validated layout).
// q_un math bit-identical to R19.
__global__ __launch_bounds__(512, 4) void kq_fused2(
    const float* __restrict__ y1,
    const float* __restrict__ ln1w, const float* __restrict__ ln1b,
    const unsigned short* __restrict__ wqT, const float* __restrict__ proj,
    const float* __restrict__ ctx2, const float* __restrict__ ksum,
    float* __restrict__ q_un, float* __restrict__ attn) {
  __shared__ unsigned short wqs[128 * 128];   // 32KB fp16
  __shared__ unsigned short xb[32 * 128];     // 8KB fp16
  __shared__ float qb[32][132];               // 16.9KB
  __shared__ unsigned short qfl[8][16][72];   // 18KB bf16 qf [wave][row][m]
  __shared__ float dvv[8][16];                // 0.5KB
  const int tid = threadIdx.x;
  const int bb = blockIdx.y;                  // 0..31
  {
    const uint4* s1 = (const uint4*)wqT; uint4* d1 = (uint4*)wqs;
    for (int i = tid; i < 2048; i += 512) d1[i] = s1[i];
  }
  const int lane = tid & 63, wvid = tid >> 6;   // 8 waves
  const int lrow = tid >> 4, c8 = tid & 15;     // LN: 32 rows x 16 chunks of 8
  const int cx = tid & 31, ry2 = tid >> 5;      // GEMM: rows ry2*2..+1, cols cx+32*cc
  const int m = lane;
  const int h = wvid;                           // head per wave
  float pr[16];
#pragma unroll
  for (int d = 0; d < 16; ++d) pr[d] = proj[m * 16 + d];
  // ctx2 B-frags (bf16, PV) + ksum-in-col0 B-frags (MFMA denominator; R14-validated)
  short8 bfr[2], bks[2];
  {
    const float* cp = ctx2 + (size_t)(bb * cH + h) * 1024;
    const float* kp = ksum + (size_t)(bb * cH + h) * cM;
#pragma unroll
    for (int kh = 0; kh < 2; ++kh) {
      short8 bfv, bkv;
#pragma unroll
      for (int j = 0; j < 8; ++j) {
        int mm = kh * 32 + (lane >> 4) * 8 + j;
        ((unsigned short*)&bfv)[j] = (unsigned short)bf16r(cp[mm * 16 + (lane & 15)]);
        ((unsigned short*)&bkv)[j] =
            ((lane & 15) == 0) ? (unsigned short)bf16r(kp[mm]) : (unsigned short)0;
      }
      bfr[kh] = bfv;
      bks[kh] = bkv;
    }
  }
  float lw[8], lb[8];
  *(float4*)&lw[0] = *(const float4*)(ln1w + c8 * 8 + 0);
  *(float4*)&lw[4] = *(const float4*)(ln1w + c8 * 8 + 4);
  *(float4*)&lb[0] = *(const float4*)(ln1b + c8 * 8 + 0);
  *(float4*)&lb[4] = *(const float4*)(ln1b + c8 * 8 + 4);
  uint4* xb4 = (uint4*)xb;
  const uint4* wq4 = (const uint4*)wqs;
  __syncthreads();

  for (int tile = blockIdx.x; tile < 96; tile += 16) {
    const int n0 = tile * 32;
    const size_t r0g = (size_t)bb * cNQ + n0;
    {  // LN1 -> xb (fp16 swizzled); row lrow, cols c8*8..+7  (R19 exact)
      const float* yr = y1 + (r0g + lrow) * 128 + c8 * 8;
      float v[8];
      *(float4*)&v[0] = *(const float4*)(yr + 0);
      *(float4*)&v[4] = *(const float4*)(yr + 4);
      float s = 0.f, q = 0.f;
#pragma unroll
      for (int j = 0; j < 8; ++j) { s += v[j]; q += v[j] * v[j]; }
#pragma unroll
      for (int o = 1; o <= 8; o <<= 1) { s += __shfl_xor(s, o); q += __shfl_xor(q, o); }
      float mu = s * (1.0f / 128.0f);
      float rs = rsqrtf(q * (1.0f / 128.0f) - mu * mu + cLNEPS);
      unsigned int us[4];
#pragma unroll
      for (int j = 0; j < 4; ++j) {
        float f0 = (v[2 * j] - mu) * rs * lw[2 * j] + lb[2 * j];
        float f1 = (v[2 * j + 1] - mu) * rs * lw[2 * j + 1] + lb[2 * j + 1];
        us[j] = f16r(f0) | (f16r(f1) << 16);
      }
      xb4[lrow * 16 + (c8 ^ (lrow & 15))] = make_uint4(us[0], us[1], us[2], us[3]);
    }
    __syncthreads();
    {  // qGEMM via v_dot2_f32_f16 (R19 exact)
      float acc[2][4] = {};
#pragma unroll 2
      for (int kg = 0; kg < 16; ++kg) {
        uint4 xv[2], wv[4];
#pragma unroll
        for (int rr = 0; rr < 2; ++rr) {
          int r = ry2 * 2 + rr;
          xv[rr] = xb4[r * 16 + (kg ^ (r & 15))];
        }
#pragma unroll
        for (int cc = 0; cc < 4; ++cc) {
          int c = cx + 32 * cc;
          wv[cc] = wq4[c * 16 + (kg ^ (c & 15))];
        }
#pragma unroll
        for (int cc = 0; cc < 4; ++cc) {
          const half2* wh = (const half2*)&wv[cc];
#pragma unroll
          for (int rr = 0; rr < 2; ++rr) {
            const half2* xh = (const half2*)&xv[rr];
#pragma unroll
            for (int p = 0; p < 4; ++p)
              acc[rr][cc] = __builtin_amdgcn_fdot2(xh[p], wh[p], acc[rr][cc], false);
          }
        }
      }
#pragma unroll
      for (int rr = 0; rr < 2; ++rr)
#pragma unroll
        for (int cc = 0; cc < 4; ++cc)
          qb[ry2 * 2 + rr][cx + 32 * cc] = acc[rr][cc];
    }
    __syncthreads();
    // ss amortization: lane L computes ss for row (L&31), EXACT R19 op order (bit-identical)
    float ssv;
    {
      int r = lane & 31;
      float4 s0 = *(const float4*)&qb[r][h * 16 + 0];
      float4 s1 = *(const float4*)&qb[r][h * 16 + 4];
      float4 s2 = *(const float4*)&qb[r][h * 16 + 8];
      float4 s3 = *(const float4*)&qb[r][h * 16 + 12];
      ssv = s0.x * s0.x + s0.y * s0.y + s0.z * s0.z + s0.w * s0.w
          + s1.x * s1.x + s1.y * s1.y + s1.z * s1.z + s1.w * s1.w
          + s2.x * s2.x + s2.y * s2.y + s2.z * s2.z + s2.w * s2.w
          + s3.x * s3.x + s3.y * s3.y + s3.z * s3.z + s3.w * s3.w;
    }
    // FAVOR: paired rows, interleaved MAX chains only (sum chain removed -> MFMA denom).
#pragma unroll
    for (int half = 0; half < 2; ++half) {
      for (int rr = 0; rr < 16; rr += 2) {
        const int rA = half * 16 + rr, rB = rA + 1;
        float4 a0 = *(const float4*)&qb[rA][h * 16 + 0];
        float4 a1 = *(const float4*)&qb[rA][h * 16 + 4];
        float4 a2 = *(const float4*)&qb[rA][h * 16 + 8];
        float4 a3 = *(const float4*)&qb[rA][h * 16 + 12];
        float4 b0 = *(const float4*)&qb[rB][h * 16 + 0];
        float4 b1 = *(const float4*)&qb[rB][h * 16 + 4];
        float4 b2 = *(const float4*)&qb[rB][h * 16 + 8];
        float4 b3 = *(const float4*)&qb[rB][h * 16 + 12];
        float dashA = a0.x * pr[0] + a0.y * pr[1] + a0.z * pr[2] + a0.w * pr[3]
                    + a1.x * pr[4] + a1.y * pr[5] + a1.z * pr[6] + a1.w * pr[7]
                    + a2.x * pr[8] + a2.y * pr[9] + a2.z * pr[10] + a2.w * pr[11]
                    + a3.x * pr[12] + a3.y * pr[13] + a3.z * pr[14] + a3.w * pr[15];
        float dashB = b0.x * pr[0] + b0.y * pr[1] + b0.z * pr[2] + b0.w * pr[3]
                    + b1.x * pr[4] + b1.y * pr[5] + b1.z * pr[6] + b1.w * pr[7]
                    + b2.x * pr[8] + b2.y * pr[9] + b2.z * pr[10] + b2.w * pr[11]
                    + b3.x * pr[12] + b3.y * pr[13] + b3.z * pr[14] + b3.w * pr[15];
        dashA *= 0.5f;
        dashB *= 0.5f;
        float ssA = __shfl(ssv, rA);
        float ssB = __shfl(ssv, rB);
        float unA = cRATIO * __expf(dashA - 0.125f * ssA);
        float unB = cRATIO * __expf(dashB - 0.125f * ssB);
        size_t baseA = (size_t)(bb * cH + h) * cNQ + n0 + rA;
        size_t baseB = baseA + 1;
        q_un[baseA * cM + m] = unA;
        q_un[baseB * cM + m] = unB;
        float mA = dashA, mB = dashB;
#pragma unroll
        for (int o = 32; o; o >>= 1) {
          float tA = __shfl_xor(mA, o);
          float tB = __shfl_xor(mB, o);
          mA = fmaxf(mA, tA);
          mB = fmaxf(mB, tB);
        }
        float qfA = unA * __expf(-mA) + cEPST;
        float qfB = unB * __expf(-mB) + cEPST;
        qfl[wvid][rr][lane] = (unsigned short)bf16r(qfA);
        qfl[wvid][rr + 1][lane] = (unsigned short)bf16r(qfB);
      }
      // MFMA denominator (ksum in col 0) then PV; wave-synchronous (dvv own-wave only)
      {
        const unsigned short* qp = &qfl[wvid][0][0];
        int ab = (lane & 15) * 72 + (lane >> 4) * 8;
        short8 a0 = *(const short8*)&qp[ab];
        short8 a1 = *(const short8*)&qp[ab + 32];
        f32x4 cd = {0.f, 0.f, 0.f, 0.f};
        cd = MFMA16x16(a0, bks[0], cd);
        cd = MFMA16x16(a1, bks[1], cd);
        if ((lane & 15) == 0) {
#pragma unroll
          for (int reg = 0; reg < 4; ++reg)
            dvv[wvid][(lane >> 4) * 4 + reg] = 1.0f / cd[reg];
        }
        f32x4 c = {0.f, 0.f, 0.f, 0.f};
        c = MFMA16x16(a0, bfr[0], c);
        c = MFMA16x16(a1, bfr[1], c);
#pragma unroll
        for (int reg = 0; reg < 4; ++reg) {
          int rloc = (lane >> 4) * 4 + reg;
          attn[(r0g + half * 16 + rloc) * cDP + h * 16 + (lane & 15)] =
              c[reg] * dvv[wvid][rloc];
        }
      }
    }
    __syncthreads();
  }
}

// ============ K6: yout = y1 + attn @ wo.T + wo_b, MFMA (R19 exact) ============
__global__ __launch_bounds__(256, 2) void k6_wo(
    const float* __restrict__ attn,
    const unsigned short* __restrict__ woT, const float* __restrict__ wob,
    const float* __restrict__ y1, float* __restrict__ yout) {
  __shared__ unsigned short wos[16384];
  __shared__ unsigned short xb[4096];
  const int tid = threadIdx.x;
  {
    const uint4* s1 = (const uint4*)woT; uint4* d1 = (uint4*)wos;
    for (int i = tid; i < 2048; i += 256) d1[i] = s1[i];
  }
  const int lane = tid & 63, wv = tid >> 6;
  const int lrow = tid >> 3, lsub = tid & 7;
  const int colbase = wv * 32;
  float wb[2];
#pragma unroll
  for (int ct = 0; ct < 2; ++ct) wb[ct] = wob[colbase + ct * 16 + (lane & 15)];
  uint4* xb4 = (uint4*)xb;
  __syncthreads();
  for (int g = blockIdx.x; g < ROWS_Q / 32; g += gridDim.x) {
    const int r0 = g * 32;
    {  // stage attn tile -> bf16 swizzled
      const float* ar = attn + (size_t)(r0 + lrow) * 128 + lsub * 16;
      float v[16];
      *(float4*)&v[0] = *(const float4*)(ar + 0);
      *(float4*)&v[4] = *(const float4*)(ar + 4);
      *(float4*)&v[8] = *(const float4*)(ar + 8);
      *(float4*)&v[12] = *(const float4*)(ar + 12);
      unsigned int us[8];
#pragma unroll
      for (int j = 0; j < 8; ++j)
        us[j] = bf16r(v[2 * j]) | (bf16r(v[2 * j + 1]) << 16);
      int s0 = (lsub * 2) ^ (lrow & 15), s1 = (lsub * 2 + 1) ^ (lrow & 15);
      xb4[lrow * 16 + s0] = make_uint4(us[0], us[1], us[2], us[3]);
      xb4[lrow * 16 + s1] = make_uint4(us[4], us[5], us[6], us[7]);
    }
    __syncthreads();
    {
      f32x4 acc[2][2] = {{{0.f,0.f,0.f,0.f},{0.f,0.f,0.f,0.f}},
                         {{0.f,0.f,0.f,0.f},{0.f,0.f,0.f,0.f}}};
#pragma unroll
      for (int kc = 0; kc < 4; ++kc) {
        short8 af[2], bfv[2];
#pragma unroll
        for (int rt = 0; rt < 2; ++rt) {
          int row = rt * 16 + (lane & 15);
          int slot = ((lane >> 4) + kc * 4) ^ (row & 15);
          af[rt] = *(const short8*)&xb[row * 128 + slot * 8];
        }
#pragma unroll
        for (int ct = 0; ct < 2; ++ct) {
          int col = colbase + ct * 16 + (lane & 15);
          int slot = ((lane >> 4) + kc * 4) ^ (col & 15);
          bfv[ct] = *(const short8*)&wos[col * 128 + slot * 8];
        }
#pragma unroll
        for (int rt = 0; rt < 2; ++rt)
#pragma unroll
          for (int ct = 0; ct < 2; ++ct)
            acc[rt][ct] = MFMA16x16(af[rt], bfv[ct], acc[rt][ct]);
      }
#pragma unroll
      for (int rt = 0; rt < 2; ++rt)
#pragma unroll
        for (int ct = 0; ct < 2; ++ct) {
          int col = colbase + ct * 16 + (lane & 15);
#pragma unroll
          for (int reg = 0; reg < 4; ++reg) {
            int row = rt * 16 + (lane >> 4) * 4 + reg;
            size_t o = (size_t)(r0 + row) * 128 + col;
            yout[o] = acc[rt][ct][reg] + wb[ct] + y1[o];
          }
        }
    }
    __syncthreads();
  }
}

// =============================== launch ===============================
extern "C" void kernel_launch(void* const* d_in, const int* in_sizes, int n_in,
                              void* d_out, int out_size, void* d_ws, size_t ws_size,
                              hipStream_t stream) {
  (void)in_sizes; (void)n_in; (void)out_size; (void)ws_size;
  const float* x = (const float*)d_in[0];
  const float* y = (const float*)d_in[1];
  const float* proj = (const float*)d_in[2];
  const float* ln1w = (const float*)d_in[3];
  const float* ln1b = (const float*)d_in[4];
  const float* ln2w = (const float*)d_in[5];
  const float* ln2b = (const float*)d_in[6];
  const float* ln4w = (const float*)d_in[7];
  const float* ln4b = (const float*)d_in[8];
  const float* fcw = (const float*)d_in[9];
  const float* fcb = (const float*)d_in[10];
  const float* prw = (const float*)d_in[11];
  const float* prb = (const float*)d_in[12];
  const float* wq = (const float*)d_in[13];
  const float* wk = (const float*)d_in[14];
  const float* wv = (const float*)d_in[15];
  const float* wo = (const float*)d_in[16];
  const float* wob = (const float*)d_in[17];

  float* out = (float*)d_out;
  float* q_un = out + 12582912;
  float* k_un = out + 62914560;

  float* ws = (float*)d_ws;
  float* y1 = ws;                          // 12,582,912
  float* kbuf = ws + 12582912;             // 6,553,600 (dead after k4)
  float* vbuf = ws + 19136512;             // 6,553,600 (dead after k5a)
  float* part_c = ws + 12582912;           // 1,572,864 (aliases kbuf; after k4)
  float* part_k = ws + 14155776;           // 98,304
  float* attn = ws + 12582912;             // 12,582,912 (aliases kbuf+vbuf; after k5a2)
  float* tmax = ws + 26476544;             // 409,600
  float* mxk = ws + 26886144;              // 256
  float* ksum = ws + 26886400;             // 16,384
  float* ctx2 = ws + 26902784;             // 262,144
  unsigned short* fcT = (unsigned short*)(ws + 27164928);   // 4 x 16384 ushorts
  unsigned short* prT = fcT + 16384;
  unsigned short* wqT = prT + 16384;
  unsigned short* woT = wqT + 16384;

  k0_prep<<<dim3(4), dim3(256), 0, stream>>>(fcw, prw, wq, wo, fcT, prT, wqT, woT);
  k1_mlp<<<dim3(512), dim3(256), 0, stream>>>(y, ln4w, ln4b, fcT, fcb, prT, prb, y1);
  k2_kv<<<dim3(400), dim3(512), 0, stream>>>(x, ln2w, ln2b, wk, wv, kbuf, vbuf);
  k4_kun<<<dim3(400), dim3(512), 0, stream>>>(kbuf, proj, k_un, tmax);
  k4b_mxk<<<dim3(128), dim3(256), 0, stream>>>(tmax, mxk);
  k5a_ctx<<<dim3(256, 6), dim3(256), 0, stream>>>(k_un, vbuf, mxk, part_c, part_k);
  k5a2_red<<<dim3(256), dim3(256), 0, stream>>>(part_c, part_k, ctx2, ksum);
  kq_fused2<<<dim3(16, 32), dim3(512), 0, stream>>>(y1, ln1w, ln1b, wqT, proj,
                                                    ctx2, ksum, q_un, attn);
  k6_wo<<<dim3(512), dim3(256), 0, stream>>>(attn, woT, wob, y1, out);
}

// Round 21
// 398.326 us; speedup vs baseline: 1.1159x; 1.0196x over previous
//
#include <hip/hip_runtime.h>
#include <math.h>

// ---------------- problem constants ----------------
constexpr int cH = 8;
constexpr int cDP = 128;
constexpr int cM = 64;
constexpr int cB = 16;
constexpr int cNCTX = 3200;
constexpr int cNQ = 3072;
constexpr int cSHIFT = 128;
constexpr int ROWS_Q = 2 * cB * cNQ;    // 98304
constexpr int ROWS_KV = cB * cNCTX;     // 51200
constexpr float cRATIO = 0.125f;
constexpr float cEPST = 0.125e-4f;
constexpr float cLNEPS = 1e-5f;

typedef float f32x4 __attribute__((ext_vector_type(4)));
typedef short short8 __attribute__((ext_vector_type(8)));
typedef _Float16 half2 __attribute__((ext_vector_type(2)));

#define MFMA16x16(a, b, c) __builtin_amdgcn_mfma_f32_16x16x32_bf16((a), (b), (c), 0, 0, 0)

__device__ __forceinline__ float wmax64(float v) {
#pragma unroll
  for (int o = 32; o; o >>= 1) v = fmaxf(v, __shfl_xor(v, o));
  return v;
}
__device__ __forceinline__ float wsum64(float v) {
#pragma unroll
  for (int o = 32; o; o >>= 1) v += __shfl_xor(v, o);
  return v;
}
__device__ __forceinline__ float gelu_f(float x) {
  return 0.5f * x * (1.0f + tanhf(0.79788456080286536f * (x + 0.044715f * x * x * x)));
}
// fp32 -> bf16 (RTNE), low 16 bits
__device__ __forceinline__ unsigned int bf16r(float f) {
  unsigned int x = __float_as_uint(f);
  return (x + 0x7fffu + ((x >> 16) & 1u)) >> 16;
}
// fp32 -> fp16 (RTNE), low 16 bits
__device__ __forceinline__ unsigned int f16r(float f) {
  _Float16 hh = (_Float16)f;
  unsigned short u;
  __builtin_memcpy(&u, &hh, 2);
  return (unsigned int)u;
}
// 8 packed bf16 (uint4) -> 8 floats
__device__ __forceinline__ void cvt8(uint4 u, float f[8]) {
  f[0] = __uint_as_float(u.x << 16);
  f[1] = __uint_as_float(u.x & 0xffff0000u);
  f[2] = __uint_as_float(u.y << 16);
  f[3] = __uint_as_float(u.y & 0xffff0000u);
  f[4] = __uint_as_float(u.z << 16);
  f[5] = __uint_as_float(u.z & 0xffff0000u);
  f[6] = __uint_as_float(u.w << 16);
  f[7] = __uint_as_float(u.w & 0xffff0000u);
}
// swizzled ushort index for element (row, k) in a [*][128] 16-bit tile
__device__ __forceinline__ int swz(int row, int k) {
  return row * 128 + ((((k >> 3) ^ (row & 15)) << 3) | (k & 7));
}

// ============ K0: weight prep -> 16-bit, [n][k] layout, pre-swizzled (R20 exact) ============
__global__ __launch_bounds__(256) void k0_prep(
    const float* __restrict__ fcw, const float* __restrict__ prw,
    const float* __restrict__ wq, const float* __restrict__ wo,
    unsigned short* __restrict__ fcT, unsigned short* __restrict__ prT,
    unsigned short* __restrict__ wqT, unsigned short* __restrict__ woT) {
  const int mat = blockIdx.x;
  const float* src = mat == 0 ? fcw : mat == 1 ? prw : mat == 2 ? wq : wo;
  unsigned short* dst = mat == 0 ? fcT : mat == 1 ? prT : mat == 2 ? wqT : woT;
  const bool tr = (mat < 2);   // fc_w/pr_w are [k][n]; wq/wo are [n][k]
  for (int i = threadIdx.x; i < 16384; i += 256) {
    int n = i >> 7, k = i & 127;
    float f = tr ? src[k * 128 + n] : src[i];
    dst[swz(n, k)] = (unsigned short)(mat == 2 ? f16r(f) : bf16r(f));
  }
}

// ============ K1: MLP (LN4 -> fc -> gelu -> pr -> +y), MFMA, 256 threads (R20 exact) ============
__global__ __launch_bounds__(256, 2) void k1_mlp(
    const float* __restrict__ y,
    const float* __restrict__ ln4w, const float* __restrict__ ln4b,
    const unsigned short* __restrict__ fcT, const float* __restrict__ fcb,
    const unsigned short* __restrict__ prT, const float* __restrict__ prb,
    float* __restrict__ y1) {
  __shared__ unsigned short wfc[16384];
  __shared__ unsigned short wpr[16384];
  __shared__ unsigned short xb[4096];
  __shared__ unsigned short hb[4096];
  const int tid = threadIdx.x;
  {
    const uint4* s1 = (const uint4*)fcT; uint4* d1 = (uint4*)wfc;
    const uint4* s2 = (const uint4*)prT; uint4* d2 = (uint4*)wpr;
    for (int i = tid; i < 2048; i += 256) { d1[i] = s1[i]; d2[i] = s2[i]; }
  }
  const int lane = tid & 63, wv = tid >> 6;
  const int lrow = tid >> 3, lsub = tid & 7;
  const int colbase = wv * 32;
  float fb[2], pb[2];
#pragma unroll
  for (int ct = 0; ct < 2; ++ct) {
    int col = colbase + ct * 16 + (lane & 15);
    fb[ct] = fcb[col];
    pb[ct] = prb[col];
  }
  float lw[16], lb[16];
  *(float4*)&lw[0] = *(const float4*)(ln4w + lsub * 16 + 0);
  *(float4*)&lw[4] = *(const float4*)(ln4w + lsub * 16 + 4);
  *(float4*)&lw[8] = *(const float4*)(ln4w + lsub * 16 + 8);
  *(float4*)&lw[12] = *(const float4*)(ln4w + lsub * 16 + 12);
  *(float4*)&lb[0] = *(const float4*)(ln4b + lsub * 16 + 0);
  *(float4*)&lb[4] = *(const float4*)(ln4b + lsub * 16 + 4);
  *(float4*)&lb[8] = *(const float4*)(ln4b + lsub * 16 + 8);
  *(float4*)&lb[12] = *(const float4*)(ln4b + lsub * 16 + 12);
  uint4* xb4 = (uint4*)xb;
  __syncthreads();

  for (int g = blockIdx.x; g < ROWS_Q / 32; g += gridDim.x) {
    const int r0 = g * 32;
    {  // LN4 -> xb (bf16 swizzled)
      const float* yr = y + (size_t)(r0 + lrow) * 128 + lsub * 16;
      float v[16];
      *(float4*)&v[0] = *(const float4*)(yr + 0);
      *(float4*)&v[4] = *(const float4*)(yr + 4);
      *(float4*)&v[8] = *(const float4*)(yr + 8);
      *(float4*)&v[12] = *(const float4*)(yr + 12);
      float s = 0.f, q = 0.f;
#pragma unroll
      for (int j = 0; j < 16; ++j) { s += v[j]; q += v[j] * v[j]; }
#pragma unroll
      for (int o = 1; o <= 4; o <<= 1) { s += __shfl_xor(s, o); q += __shfl_xor(q, o); }
      float mu = s * (1.0f / 128.0f);
      float rs = rsqrtf(q * (1.0f / 128.0f) - mu * mu + cLNEPS);
      unsigned int us[8];
#pragma unroll
      for (int j = 0; j < 8; ++j) {
        float f0 = (v[2 * j] - mu) * rs * lw[2 * j] + lb[2 * j];
        float f1 = (v[2 * j + 1] - mu) * rs * lw[2 * j + 1] + lb[2 * j + 1];
        us[j] = bf16r(f0) | (bf16r(f1) << 16);
      }
      int s0 = (lsub * 2) ^ (lrow & 15), s1 = (lsub * 2 + 1) ^ (lrow & 15);
      xb4[lrow * 16 + s0] = make_uint4(us[0], us[1], us[2], us[3]);
      xb4[lrow * 16 + s1] = make_uint4(us[4], us[5], us[6], us[7]);
    }
    __syncthreads();
    {  // GEMM1 (MFMA) + gelu -> hb
      f32x4 acc[2][2] = {{{0.f,0.f,0.f,0.f},{0.f,0.f,0.f,0.f}},
                         {{0.f,0.f,0.f,0.f},{0.f,0.f,0.f,0.f}}};
#pragma unroll
      for (int kc = 0; kc < 4; ++kc) {
        short8 af[2], bfv[2];
#pragma unroll
        for (int rt = 0; rt < 2; ++rt) {
          int row = rt * 16 + (lane & 15);
          int slot = ((lane >> 4) + kc * 4) ^ (row & 15);
          af[rt] = *(const short8*)&xb[row * 128 + slot * 8];
        }
#pragma unroll
        for (int ct = 0; ct < 2; ++ct) {
          int col = colbase + ct * 16 + (lane & 15);
          int slot = ((lane >> 4) + kc * 4) ^ (col & 15);
          bfv[ct] = *(const short8*)&wfc[col * 128 + slot * 8];
        }
#pragma unroll
        for (int rt = 0; rt < 2; ++rt)
#pragma unroll
          for (int ct = 0; ct < 2; ++ct)
            acc[rt][ct] = MFMA16x16(af[rt], bfv[ct], acc[rt][ct]);
      }
#pragma unroll
      for (int rt = 0; rt < 2; ++rt)
#pragma unroll
        for (int ct = 0; ct < 2; ++ct) {
          int col = colbase + ct * 16 + (lane & 15);
#pragma unroll
          for (int reg = 0; reg < 4; ++reg) {
            int row = rt * 16 + (lane >> 4) * 4 + reg;
            hb[swz(row, col)] = (unsigned short)bf16r(gelu_f(acc[rt][ct][reg] + fb[ct]));
          }
        }
    }
    __syncthreads();
    {  // GEMM2 (MFMA) + bias + residual -> y1
      f32x4 a2[2][2] = {{{0.f,0.f,0.f,0.f},{0.f,0.f,0.f,0.f}},
                        {{0.f,0.f,0.f,0.f},{0.f,0.f,0.f,0.f}}};
#pragma unroll
      for (int kc = 0; kc < 4; ++kc) {
        short8 af[2], bfv[2];
#pragma unroll
        for (int rt = 0; rt < 2; ++rt) {
          int row = rt * 16 + (lane & 15);
          int slot = ((lane >> 4) + kc * 4) ^ (row & 15);
          af[rt] = *(const short8*)&hb[row * 128 + slot * 8];
        }
#pragma unroll
        for (int ct = 0; ct < 2; ++ct) {
          int col = colbase + ct * 16 + (lane & 15);
          int slot = ((lane >> 4) + kc * 4) ^ (col & 15);
          bfv[ct] = *(const short8*)&wpr[col * 128 + slot * 8];
        }
#pragma unroll
        for (int rt = 0; rt < 2; ++rt)
#pragma unroll
          for (int ct = 0; ct < 2; ++ct)
            a2[rt][ct] = MFMA16x16(af[rt], bfv[ct], a2[rt][ct]);
      }
#pragma unroll
      for (int rt = 0; rt < 2; ++rt)
#pragma unroll
        for (int ct = 0; ct < 2; ++ct) {
          int col = colbase + ct * 16 + (lane & 15);
#pragma unroll
          for (int reg = 0; reg < 4; ++reg) {
            int row = rt * 16 + (lane >> 4) * 4 + reg;
            size_t o = (size_t)(r0 + row) * 128 + col;
            y1[o] = a2[rt][ct][reg] + pb[ct] + y[o];
          }
        }
    }
    __syncthreads();
  }
}

// ============ K2: LN2(x) -> k,v projections (R20 exact) ============
__global__ __launch_bounds__(512) void k2_kv(
    const float* __restrict__ x,
    const float* __restrict__ ln2w, const float* __restrict__ ln2b,
    const float* __restrict__ wkw, const float* __restrict__ wvw,
    float* __restrict__ kbuf, float* __restrict__ vbuf) {
  __shared__ float wkT[32 * cDP];
  __shared__ float wvT[32 * cDP];
  __shared__ float xbs[16][32];
  const int tid = threadIdx.x;
  for (int i = tid; i < 32 * cDP; i += 512) {
    int j = i >> 5, d = i & 31;
    wkT[d * cDP + j] = wkw[i];
    wvT[d * cDP + j] = wvw[i];
  }
  const int dl = tid & 31, rl = tid >> 5;
  const int col = tid & 127, rh = tid >> 7;
  const float l2w = ln2w[dl], l2b = ln2b[dl];
  __syncthreads();
  for (int g = blockIdx.x; g < ROWS_KV / 16; g += gridDim.x) {
    const int r0 = g * 16;
    __syncthreads();
    {
      float v = x[(size_t)(r0 + rl) * 32 + dl];
      float s = v, q = v * v;
#pragma unroll
      for (int o = 16; o; o >>= 1) { s += __shfl_xor(s, o); q += __shfl_xor(q, o); }
      float mu = s * (1.0f / 32.0f);
      float var = q * (1.0f / 32.0f) - mu * mu;
      xbs[rl][dl] = (v - mu) * rsqrtf(var + cLNEPS) * l2w + l2b;
    }
    __syncthreads();
    float ak0 = 0, ak1 = 0, ak2 = 0, ak3 = 0, av0 = 0, av1 = 0, av2 = 0, av3 = 0;
    for (int d = 0; d < 32; d += 4) {
      float4 v0 = *(const float4*)&xbs[rh * 4 + 0][d];
      float4 v1 = *(const float4*)&xbs[rh * 4 + 1][d];
      float4 v2 = *(const float4*)&xbs[rh * 4 + 2][d];
      float4 v3 = *(const float4*)&xbs[rh * 4 + 3][d];
      float k0 = wkT[(d + 0) * cDP + col], k1 = wkT[(d + 1) * cDP + col];
      float k2 = wkT[(d + 2) * cDP + col], k3 = wkT[(d + 3) * cDP + col];
      float u0 = wvT[(d + 0) * cDP + col], u1 = wvT[(d + 1) * cDP + col];
      float u2 = wvT[(d + 2) * cDP + col], u3 = wvT[(d + 3) * cDP + col];
      ak0 += v0.x * k0 + v0.y * k1 + v0.z * k2 + v0.w * k3;
      ak1 += v1.x * k0 + v1.y * k1 + v1.z * k2 + v1.w * k3;
      ak2 += v2.x * k0 + v2.y * k1 + v2.z * k2 + v2.w * k3;
      ak3 += v3.x * k0 + v3.y * k1 + v3.z * k2 + v3.w * k3;
      av0 += v0.x * u0 + v0.y * u1 + v0.z * u2 + v0.w * u3;
      av1 += v1.x * u0 + v1.y * u1 + v1.z * u2 + v1.w * u3;
      av2 += v2.x * u0 + v2.y * u1 + v2.z * u2 + v2.w * u3;
      av3 += v3.x * u0 + v3.y * u1 + v3.z * u2 + v3.w * u3;
    }
    kbuf[(size_t)(r0 + rh * 4 + 0) * cDP + col] = ak0;
    kbuf[(size_t)(r0 + rh * 4 + 1) * cDP + col] = ak1;
    kbuf[(size_t)(r0 + rh * 4 + 2) * cDP + col] = ak2;
    kbuf[(size_t)(r0 + rh * 4 + 3) * cDP + col] = ak3;
    vbuf[(size_t)(r0 + rh * 4 + 0) * cDP + col] = av0;
    vbuf[(size_t)(r0 + rh * 4 + 1) * cDP + col] = av1;
    vbuf[(size_t)(r0 + rh * 4 + 2) * cDP + col] = av2;
    vbuf[(size_t)(r0 + rh * 4 + 3) * cDP + col] = av3;
  }
}

// ============ K4: k features + windowed writes; 4-row groups, interleaved max chains ============
__global__ __launch_bounds__(512) void k4_kun(
    const float* __restrict__ kbuf, const float* __restrict__ proj,
    float* __restrict__ k_un, float* __restrict__ tmax) {
  __shared__ float kb[16][cDP];
  const int tid = threadIdx.x;
  const int m = tid & 63, h = tid >> 6, lane = tid & 63;
  float pr[16];
#pragma unroll
  for (int d = 0; d < 16; ++d) pr[d] = proj[m * 16 + d];
  for (int g = blockIdx.x; g < ROWS_KV / 16; g += gridDim.x) {
    const int r0 = g * 16;
    __syncthreads();
    for (int i = tid; i < 16 * cDP; i += 512)
      kb[i >> 7][i & 127] = kbuf[(size_t)(r0 + (i >> 7)) * cDP + (i & 127)];
    __syncthreads();
    const int b = r0 / cNCTX;   // 16-row tile never crosses batch boundary (3200 % 16 == 0)
    for (int r4 = 0; r4 < 16; r4 += 4) {
      float dashv[4];
#pragma unroll
      for (int j = 0; j < 4; ++j) {
        int r = r4 + j;
        float4 q0 = *(const float4*)&kb[r][h * 16 + 0];
        float4 q1 = *(const float4*)&kb[r][h * 16 + 4];
        float4 q2 = *(const float4*)&kb[r][h * 16 + 8];
        float4 q3 = *(const float4*)&kb[r][h * 16 + 12];
        float dash = q0.x * pr[0] + q0.y * pr[1] + q0.z * pr[2] + q0.w * pr[3]
                   + q1.x * pr[4] + q1.y * pr[5] + q1.z * pr[6] + q1.w * pr[7]
                   + q2.x * pr[8] + q2.y * pr[9] + q2.z * pr[10] + q2.w * pr[11]
                   + q3.x * pr[12] + q3.y * pr[13] + q3.z * pr[14] + q3.w * pr[15];
        dash *= 0.5f;
        float ss = q0.x * q0.x + q0.y * q0.y + q0.z * q0.z + q0.w * q0.w
                 + q1.x * q1.x + q1.y * q1.y + q1.z * q1.z + q1.w * q1.w
                 + q2.x * q2.x + q2.y * q2.y + q2.z * q2.z + q2.w * q2.w
                 + q3.x * q3.x + q3.y * q3.y + q3.z * q3.z + q3.w * q3.w;
        dashv[j] = dash;
        float un = cRATIO * __expf(dash - 0.125f * ss);
        int t = r0 + r - b * cNCTX;
        if (t < cNQ)
          k_un[((size_t)(b * cH + h) * cNQ + t) * cM + m] = un;
        if (t >= cSHIFT)
          k_un[((size_t)((b + cB) * cH + h) * cNQ + (t - cSHIFT)) * cM + m] = un;
      }
      // 4 interleaved max butterflies (fmax exact -> bit-identical to serial wmax64)
      float m0 = dashv[0], m1 = dashv[1], m2 = dashv[2], m3 = dashv[3];
#pragma unroll
      for (int o = 32; o; o >>= 1) {
        float t0 = __shfl_xor(m0, o), t1 = __shfl_xor(m1, o);
        float t2 = __shfl_xor(m2, o), t3 = __shfl_xor(m3, o);
        m0 = fmaxf(m0, t0); m1 = fmaxf(m1, t1);
        m2 = fmaxf(m2, t2); m3 = fmaxf(m3, t3);
      }
      if (lane == 0) {
        int tb = (b * cH + h) * cNCTX + (r0 - b * cNCTX) + r4;
        tmax[tb + 0] = m0;
        tmax[tb + 1] = m1;
        tmax[tb + 2] = m2;
        tmax[tb + 3] = m3;
      }
    }
  }
}

// ============ K4b: windowed max (R20 exact) ============
__global__ __launch_bounds__(256) void k4b_mxk(
    const float* __restrict__ tmax, float* __restrict__ mxk) {
  const int bh = blockIdx.x;
  const int tid = threadIdx.x;
  float m0 = -1e30f, m1 = -1e30f;
  for (int t = tid; t < cNCTX; t += 256) {
    float v = tmax[bh * cNCTX + t];
    if (t < cNQ) m0 = fmaxf(m0, v);
    if (t >= cSHIFT) m1 = fmaxf(m1, v);
  }
  __shared__ float s0[256], s1[256];
  s0[tid] = m0; s1[tid] = m1;
  __syncthreads();
  for (int s = 128; s; s >>= 1) {
    if (tid < s) { s0[tid] = fmaxf(s0[tid], s0[tid + s]); s1[tid] = fmaxf(s1[tid], s1[tid + s]); }
    __syncthreads();
  }
  if (tid == 0) { mxk[bh] = s0[0]; mxk[bh + 128] = s1[0]; }
}

// ============ K5a: partial ctx/ksum over 512-token chunks (R20 exact) ============
__global__ __launch_bounds__(256) void k5a_ctx(
    const float* __restrict__ k_un, const float* __restrict__ vbuf,
    const float* __restrict__ mxk,
    float* __restrict__ part_c, float* __restrict__ part_k) {
  const int bbh = blockIdx.x;   // 0..255
  const int ch = blockIdx.y;    // 0..5
  const int bb = bbh >> 3, h = bbh & 7;
  const int b = bb & 15, toff = (bb >> 4) * cSHIFT;
  const float ek = expf(-mxk[bbh]);
  const int tid = threadIdx.x, m = tid & 63, eq = tid >> 6;
  __shared__ float ub[64][64];
  __shared__ float vb[64][16];
  float c0 = 0, c1 = 0, c2 = 0, c3 = 0, ks = 0;
  const int nb = ch * 512;
  for (int n0 = nb; n0 < nb + 512; n0 += 64) {
    for (int i = tid; i < 64 * 64; i += 256)
      ub[i >> 6][i & 63] = k_un[((size_t)bbh * cNQ + n0 + (i >> 6)) * cM + (i & 63)];
    for (int i = tid; i < 64 * 16; i += 256)
      vb[i >> 4][i & 15] = vbuf[((size_t)(b * cNCTX) + toff + n0 + (i >> 4)) * cDP + h * 16 + (i & 15)];
    __syncthreads();
#pragma unroll 4
    for (int nn = 0; nn < 64; ++nn) {
      float kf = ub[nn][m] * ek + cEPST;
      ks += kf;
      float4 vv = *(const float4*)&vb[nn][eq * 4];
      c0 += kf * vv.x; c1 += kf * vv.y; c2 += kf * vv.z; c3 += kf * vv.w;
    }
    __syncthreads();
  }
  size_t po = (size_t)ch * 256 + bbh;
  part_c[po * 1024 + m * 16 + eq * 4 + 0] = c0;
  part_c[po * 1024 + m * 16 + eq * 4 + 1] = c1;
  part_c[po * 1024 + m * 16 + eq * 4 + 2] = c2;
  part_c[po * 1024 + m * 16 + eq * 4 + 3] = c3;
  if (eq == 0) part_k[po * 64 + m] = ks;
}

__global__ __launch_bounds__(256) void k5a2_red(
    const float* __restrict__ part_c, const float* __restrict__ part_k,
    float* __restrict__ ctx2, float* __restrict__ ksum) {
  const int bbh = blockIdx.x;
  const int tid = threadIdx.x;
  for (int i = tid; i < 1024; i += 256) {
    float s = 0;
#pragma unroll
    for (int ch = 0; ch < 6; ++ch) s += part_c[((size_t)ch * 256 + bbh) * 1024 + i];
    ctx2[bbh * 1024 + i] = s;
  }
  if (tid < 64) {
    float s = 0;
#pragma unroll
    for (int ch = 0; ch < 6; ++ch) s += part_k[((size_t)ch * 256 + bbh) * 64 + tid];
    ksum[bbh * cM + tid] = s;
  }
}

// ============ KQ2 (512 threads): LN1(f16) -> fdot2 qGEMM -> FAVOR (4-way max) -> MFMA denom + PV ============
__global__ __launch_bounds__(512, 4) void kq_fused2(
    const float* __restrict__ y1,
    const float* __restrict__ ln1w, const float* __restrict__ ln1b,
    const unsigned short* __restrict__ wqT, const float* __restrict__ proj,
    const float* __restrict__ ctx2, const float* __restrict__ ksum,
    float* __restrict__ q_un, float* __restrict__ attn) {
  __shared__ unsigned short wqs[128 * 128];   // 32KB fp16
  __shared__ unsigned short xb[32 * 128];     // 8KB fp16
  __shared__ float qb[32][132];               // 16.9KB
  __shared__ unsigned short qfl[8][16][72];   // 18KB bf16 qf [wave][row][m]
  __shared__ float dvv[8][16];                // 0.5KB
  const int tid = threadIdx.x;
  const int bb = blockIdx.y;                  // 0..31
  {
    const uint4* s1 = (const uint4*)wqT; uint4* d1 = (uint4*)wqs;
    for (int i = tid; i < 2048; i += 512) d1[i] = s1[i];
  }
  const int lane = tid & 63, wvid = tid >> 6;   // 8 waves
  const int lrow = tid >> 4, c8 = tid & 15;     // LN: 32 rows x 16 chunks of 8
  const int cx = tid & 31, ry2 = tid >> 5;      // GEMM: rows ry2*2..+1, cols cx+32*cc
  const int m = lane;
  const int h = wvid;                           // head per wave
  float pr[16];
#pragma unroll
  for (int d = 0; d < 16; ++d) pr[d] = proj[m * 16 + d];
  // ctx2 B-frags (bf16, PV) + ksum-in-col0 B-frags (MFMA denominator; R20-proven)
  short8 bfr[2], bks[2];
  {
    const float* cp = ctx2 + (size_t)(bb * cH + h) * 1024;
    const float* kp = ksum + (size_t)(bb * cH + h) * cM;
#pragma unroll
    for (int kh = 0; kh < 2; ++kh) {
      short8 bfv, bkv;
#pragma unroll
      for (int j = 0; j < 8; ++j) {
        int mm = kh * 32 + (lane >> 4) * 8 + j;
        ((unsigned short*)&bfv)[j] = (unsigned short)bf16r(cp[mm * 16 + (lane & 15)]);
        ((unsigned short*)&bkv)[j] =
            ((lane & 15) == 0) ? (unsigned short)bf16r(kp[mm]) : (unsigned short)0;
      }
      bfr[kh] = bfv;
      bks[kh] = bkv;
    }
  }
  float lw[8], lb[8];
  *(float4*)&lw[0] = *(const float4*)(ln1w + c8 * 8 + 0);
  *(float4*)&lw[4] = *(const float4*)(ln1w + c8 * 8 + 4);
  *(float4*)&lb[0] = *(const float4*)(ln1b + c8 * 8 + 0);
  *(float4*)&lb[4] = *(const float4*)(ln1b + c8 * 8 + 4);
  uint4* xb4 = (uint4*)xb;
  const uint4* wq4 = (const uint4*)wqs;
  __syncthreads();

  for (int tile = blockIdx.x; tile < 96; tile += 16) {
    const int n0 = tile * 32;
    const size_t r0g = (size_t)bb * cNQ + n0;
    {  // LN1 -> xb (fp16 swizzled); row lrow, cols c8*8..+7  (R20 exact)
      const float* yr = y1 + (r0g + lrow) * 128 + c8 * 8;
      float v[8];
      *(float4*)&v[0] = *(const float4*)(yr + 0);
      *(float4*)&v[4] = *(const float4*)(yr + 4);
      float s = 0.f, q = 0.f;
#pragma unroll
      for (int j = 0; j < 8; ++j) { s += v[j]; q += v[j] * v[j]; }
#pragma unroll
      for (int o = 1; o <= 8; o <<= 1) { s += __shfl_xor(s, o); q += __shfl_xor(q, o); }
      float mu = s * (1.0f / 128.0f);
      float rs = rsqrtf(q * (1.0f / 128.0f) - mu * mu + cLNEPS);
      unsigned int us[4];
#pragma unroll
      for (int j = 0; j < 4; ++j) {
        float f0 = (v[2 * j] - mu) * rs * lw[2 * j] + lb[2 * j];
        float f1 = (v[2 * j + 1] - mu) * rs * lw[2 * j + 1] + lb[2 * j + 1];
        us[j] = f16r(f0) | (f16r(f1) << 16);
      }
      xb4[lrow * 16 + (c8 ^ (lrow & 15))] = make_uint4(us[0], us[1], us[2], us[3]);
    }
    __syncthreads();
    {  // qGEMM via v_dot2_f32_f16 (R20 exact)
      float acc[2][4] = {};
#pragma unroll 2
      for (int kg = 0; kg < 16; ++kg) {
        uint4 xv[2], wv[4];
#pragma unroll
        for (int rr = 0; rr < 2; ++rr) {
          int r = ry2 * 2 + rr;
          xv[rr] = xb4[r * 16 + (kg ^ (r & 15))];
        }
#pragma unroll
        for (int cc = 0; cc < 4; ++cc) {
          int c = cx + 32 * cc;
          wv[cc] = wq4[c * 16 + (kg ^ (c & 15))];
        }
#pragma unroll
        for (int cc = 0; cc < 4; ++cc) {
          const half2* wh = (const half2*)&wv[cc];
#pragma unroll
          for (int rr = 0; rr < 2; ++rr) {
            const half2* xh = (const half2*)&xv[rr];
#pragma unroll
            for (int p = 0; p < 4; ++p)
              acc[rr][cc] = __builtin_amdgcn_fdot2(xh[p], wh[p], acc[rr][cc], false);
          }
        }
      }
#pragma unroll
      for (int rr = 0; rr < 2; ++rr)
#pragma unroll
        for (int cc = 0; cc < 4; ++cc)
          qb[ry2 * 2 + rr][cx + 32 * cc] = acc[rr][cc];
    }
    __syncthreads();
    // ss amortization: lane L computes ss for row (L&31), EXACT R20 op order
    float ssv;
    {
      int r = lane & 31;
      float4 s0 = *(const float4*)&qb[r][h * 16 + 0];
      float4 s1 = *(const float4*)&qb[r][h * 16 + 4];
      float4 s2 = *(const float4*)&qb[r][h * 16 + 8];
      float4 s3 = *(const float4*)&qb[r][h * 16 + 12];
      ssv = s0.x * s0.x + s0.y * s0.y + s0.z * s0.z + s0.w * s0.w
          + s1.x * s1.x + s1.y * s1.y + s1.z * s1.z + s1.w * s1.w
          + s2.x * s2.x + s2.y * s2.y + s2.z * s2.z + s2.w * s2.w
          + s3.x * s3.x + s3.y * s3.y + s3.z * s3.z + s3.w * s3.w;
    }
    // FAVOR: 4-row groups with four interleaved MAX chains (fmax exact -> bit-identical).
#pragma unroll
    for (int half = 0; half < 2; ++half) {
      for (int rr = 0; rr < 16; rr += 4) {
        float dashv[4], unv[4];
#pragma unroll
        for (int j = 0; j < 4; ++j) {
          int r = half * 16 + rr + j;
          float4 a0 = *(const float4*)&qb[r][h * 16 + 0];
          float4 a1 = *(const float4*)&qb[r][h * 16 + 4];
          float4 a2 = *(const float4*)&qb[r][h * 16 + 8];
          float4 a3 = *(const float4*)&qb[r][h * 16 + 12];
          float dash = a0.x * pr[0] + a0.y * pr[1] + a0.z * pr[2] + a0.w * pr[3]
                     + a1.x * pr[4] + a1.y * pr[5] + a1.z * pr[6] + a1.w * pr[7]
                     + a2.x * pr[8] + a2.y * pr[9] + a2.z * pr[10] + a2.w * pr[11]
                     + a3.x * pr[12] + a3.y * pr[13] + a3.z * pr[14] + a3.w * pr[15];
          dash *= 0.5f;
          dashv[j] = dash;
          float ss = __shfl(ssv, r);
          unv[j] = cRATIO * __expf(dash - 0.125f * ss);
          q_un[((size_t)(bb * cH + h) * cNQ + n0 + r) * cM + m] = unv[j];
        }
        float m0 = dashv[0], m1 = dashv[1], m2 = dashv[2], m3 = dashv[3];
#pragma unroll
        for (int o = 32; o; o >>= 1) {
          float t0 = __shfl_xor(m0, o), t1 = __shfl_xor(m1, o);
          float t2 = __shfl_xor(m2, o), t3 = __shfl_xor(m3, o);
          m0 = fmaxf(m0, t0); m1 = fmaxf(m1, t1);
          m2 = fmaxf(m2, t2); m3 = fmaxf(m3, t3);
        }
        qfl[wvid][rr + 0][lane] = (unsigned short)bf16r(unv[0] * __expf(-m0) + cEPST);
        qfl[wvid][rr + 1][lane] = (unsigned short)bf16r(unv[1] * __expf(-m1) + cEPST);
        qfl[wvid][rr + 2][lane] = (unsigned short)bf16r(unv[2] * __expf(-m2) + cEPST);
        qfl[wvid][rr + 3][lane] = (unsigned short)bf16r(unv[3] * __expf(-m3) + cEPST);
      }
      // MFMA denominator (ksum in col 0) then PV; wave-synchronous (dvv own-wave only)
      {
        const unsigned short* qp = &qfl[wvid][0][0];
        int ab = (lane & 15) * 72 + (lane >> 4) * 8;
        short8 a0 = *(const short8*)&qp[ab];
        short8 a1 = *(const short8*)&qp[ab + 32];
        f32x4 cd = {0.f, 0.f, 0.f, 0.f};
        cd = MFMA16x16(a0, bks[0], cd);
        cd = MFMA16x16(a1, bks[1], cd);
        if ((lane & 15) == 0) {
#pragma unroll
          for (int reg = 0; reg < 4; ++reg)
            dvv[wvid][(lane >> 4) * 4 + reg] = 1.0f / cd[reg];
        }
        f32x4 c = {0.f, 0.f, 0.f, 0.f};
        c = MFMA16x16(a0, bfr[0], c);
        c = MFMA16x16(a1, bfr[1], c);
#pragma unroll
        for (int reg = 0; reg < 4; ++reg) {
          int rloc = (lane >> 4) * 4 + reg;
          attn[(r0g + half * 16 + rloc) * cDP + h * 16 + (lane & 15)] =
              c[reg] * dvv[wvid][rloc];
        }
      }
    }
    __syncthreads();
  }
}

// ============ K6: yout = y1 + attn @ wo.T + wo_b, MFMA (R20 exact) ============
__global__ __launch_bounds__(256, 2) void k6_wo(
    const float* __restrict__ attn,
    const unsigned short* __restrict__ woT, const float* __restrict__ wob,
    const float* __restrict__ y1, float* __restrict__ yout) {
  __shared__ unsigned short wos[16384];
  __shared__ unsigned short xb[4096];
  const int tid = threadIdx.x;
  {
    const uint4* s1 = (const uint4*)woT; uint4* d1 = (uint4*)wos;
    for (int i = tid; i < 2048; i += 256) d1[i] = s1[i];
  }
  const int lane = tid & 63, wv = tid >> 6;
  const int lrow = tid >> 3, lsub = tid & 7;
  const int colbase = wv * 32;
  float wb[2];
#pragma unroll
  for (int ct = 0; ct < 2; ++ct) wb[ct] = wob[colbase + ct * 16 + (lane & 15)];
  uint4* xb4 = (uint4*)xb;
  __syncthreads();
  for (int g = blockIdx.x; g < ROWS_Q / 32; g += gridDim.x) {
    const int r0 = g * 32;
    {  // stage attn tile -> bf16 swizzled
      const float* ar = attn + (size_t)(r0 + lrow) * 128 + lsub * 16;
      float v[16];
      *(float4*)&v[0] = *(const float4*)(ar + 0);
      *(float4*)&v[4] = *(const float4*)(ar + 4);
      *(float4*)&v[8] = *(const float4*)(ar + 8);
      *(float4*)&v[12] = *(const float4*)(ar + 12);
      unsigned int us[8];
#pragma unroll
      for (int j = 0; j < 8; ++j)
        us[j] = bf16r(v[2 * j]) | (bf16r(v[2 * j + 1]) << 16);
      int s0 = (lsub * 2) ^ (lrow & 15), s1 = (lsub * 2 + 1) ^ (lrow & 15);
      xb4[lrow * 16 + s0] = make_uint4(us[0], us[1], us[2], us[3]);
      xb4[lrow * 16 + s1] = make_uint4(us[4], us[5], us[6], us[7]);
    }
    __syncthreads();
    {
      f32x4 acc[2][2] = {{{0.f,0.f,0.f,0.f},{0.f,0.f,0.f,0.f}},
                         {{0.f,0.f,0.f,0.f},{0.f,0.f,0.f,0.f}}};
#pragma unroll
      for (int kc = 0; kc < 4; ++kc) {
        short8 af[2], bfv[2];
#pragma unroll
        for (int rt = 0; rt < 2; ++rt) {
          int row = rt * 16 + (lane & 15);
          int slot = ((lane >> 4) + kc * 4) ^ (row & 15);
          af[rt] = *(const short8*)&xb[row * 128 + slot * 8];
        }
#pragma unroll
        for (int ct = 0; ct < 2; ++ct) {
          int col = colbase + ct * 16 + (lane & 15);
          int slot = ((lane >> 4) + kc * 4) ^ (col & 15);
          bfv[ct] = *(const short8*)&wos[col * 128 + slot * 8];
        }
#pragma unroll
        for (int rt = 0; rt < 2; ++rt)
#pragma unroll
          for (int ct = 0; ct < 2; ++ct)
            acc[rt][ct] = MFMA16x16(af[rt], bfv[ct], acc[rt][ct]);
      }
#pragma unroll
      for (int rt = 0; rt < 2; ++rt)
#pragma unroll
        for (int ct = 0; ct < 2; ++ct) {
          int col = colbase + ct * 16 + (lane & 15);
#pragma unroll
          for (int reg = 0; reg < 4; ++reg) {
            int row = rt * 16 + (lane >> 4) * 4 + reg;
            size_t o = (size_t)(r0 + row) * 128 + col;
            yout[o] = acc[rt][ct][reg] + wb[ct] + y1[o];
          }
        }
    }
    __syncthreads();
  }
}

// =============================== launch ===============================
extern "C" void kernel_launch(void* const* d_in, const int* in_sizes, int n_in,
                              void* d_out, int out_size, void* d_ws, size_t ws_size,
                              hipStream_t stream) {
  (void)in_sizes; (void)n_in; (void)out_size; (void)ws_size;
  const float* x = (const float*)d_in[0];
  const float* y = (const float*)d_in[1];
  const float* proj = (const float*)d_in[2];
  const float* ln1w = (const float*)d_in[3];
  const float* ln1b = (const float*)d_in[4];
  const float* ln2w = (const float*)d_in[5];
  const float* ln2b = (const float*)d_in[6];
  const float* ln4w = (const float*)d_in[7];
  const float* ln4b = (const float*)d_in[8];
  const float* fcw = (const float*)d_in[9];
  const float* fcb = (const float*)d_in[10];
  const float* prw = (const float*)d_in[11];
  const float* prb = (const float*)d_in[12];
  const float* wq = (const float*)d_in[13];
  const float* wk = (const float*)d_in[14];
  const float* wv = (const float*)d_in[15];
  const float* wo = (const float*)d_in[16];
  const float* wob = (const float*)d_in[17];

  float* out = (float*)d_out;
  float* q_un = out + 12582912;
  float* k_un = out + 62914560;

  float* ws = (float*)d_ws;
  float* y1 = ws;                          // 12,582,912
  float* kbuf = ws + 12582912;             // 6,553,600 (dead after k4)
  float* vbuf = ws + 19136512;             // 6,553,600 (dead after k5a)
  float* part_c = ws + 12582912;           // 1,572,864 (aliases kbuf; after k4)
  float* part_k = ws + 14155776;           // 98,304
  float* attn = ws + 12582912;             // 12,582,912 (aliases kbuf+vbuf; after k5a2)
  float* tmax = ws + 26476544;             // 409,600
  float* mxk = ws + 26886144;              // 256
  float* ksum = ws + 26886400;             // 16,384
  float* ctx2 = ws + 26902784;             // 262,144
  unsigned short* fcT = (unsigned short*)(ws + 27164928);   // 4 x 16384 ushorts
  unsigned short* prT = fcT + 16384;
  unsigned short* wqT = prT + 16384;
  unsigned short* woT = wqT + 16384;

  k0_prep<<<dim3(4), dim3(256), 0, stream>>>(fcw, prw, wq, wo, fcT, prT, wqT, woT);
  k1_mlp<<<dim3(512), dim3(256), 0, stream>>>(y, ln4w, ln4b, fcT, fcb, prT, prb, y1);
  k2_kv<<<dim3(400), dim3(512), 0, stream>>>(x, ln2w, ln2b, wk, wv, kbuf, vbuf);
  k4_kun<<<dim3(400), dim3(512), 0, stream>>>(kbuf, proj, k_un, tmax);
  k4b_mxk<<<dim3(128), dim3(256), 0, stream>>>(tmax, mxk);
  k5a_ctx<<<dim3(256, 6), dim3(256), 0, stream>>>(k_un, vbuf, mxk, part_c, part_k);
  k5a2_red<<<dim3(256), dim3(256), 0, stream>>>(part_c, part_k, ctx2, ksum);
  kq_fused2<<<dim3(16, 32), dim3(512), 0, stream>>>(y1, ln1w, ln1b, wqT, proj,
                                                    ctx2, ksum, q_un, attn);
  k6_wo<<<dim3(512), dim3(256), 0, stream>>>(attn, woT, wob, y1, out);
}